// Round 8
// baseline (2393.008 us; speedup 1.0000x reference)
//
#include <hip/hip_runtime.h>
#include <math.h>

// Problem constants: B=8, T=8, CIN=64, FN=64, H=W=32, HW=1024, GROUPS=8
// ws layout (floats):
//  ic     @ 0        (524288)
//  ih     @ 524288   (524288)
//  im     @ 1048576  (524288)
//  gates  @ 1572864  (2097152)   [conv out; reused as g2 (z2 out) later]
//  gnstat @ 3670016  (256)
//  qkv    @ 3670272  (1572864)   [B][192][1024]: Q 0-63, Kh 64-127, Vh 128-191
//  mkv    @ 5243136  (1048576)   [B][128][1024]: Km 0-63, Vm 64-127
//  stats  @ 6291712  (65536)     [b][att][mh][{M,D}][1024]
//  cat2   @ 6357248  (1048576)   [B][128][1024]: Zc rows 0-63, oh rows 64-127
//  zc0    @ 7405824  (1048576)   [B][128][1024] partial Z (n-half 0)
//  wpack  @ 8454400  (184320)    MFMA-packed conv weights (bf16)
//  wproj  @ 8638720  (26624)     bf16 proj weights: h@0 m@12288 z1@20480 z2@28672
//  zc1    @ 8665344  (1048576)   partial Z (n-half 1)
// total 9713920 floats = 38.9 MB

#define DEV __device__ __forceinline__

DEV float sigm(float x) { return 1.0f / (1.0f + __expf(-x)); }

DEV unsigned short f2bf(float f) {
  union { float f; unsigned u; } v; v.f = f;
  unsigned r = v.u + 0x7FFF + ((v.u >> 16) & 1);  // RNE
  return (unsigned short)(r >> 16);
}

DEV unsigned pk2(float a, float b) {
  return (unsigned)f2bf(a) | ((unsigned)f2bf(b) << 16);
}

typedef float f32x4 __attribute__((ext_vector_type(4)));
typedef short bf16x8 __attribute__((ext_vector_type(8)));

// ---------------------------------------------------------------------------
// Prepack conv weights to bf16 MFMA layout:
// wpack[oh 2][s 36][ocl 128][ci 40]   (ci 0..31 real, 32..39 = 0)
// ---------------------------------------------------------------------------
__global__ __launch_bounds__(256) void wprep_kernel(
    const float* __restrict__ w, unsigned short* __restrict__ wpack)
{
  int e = blockIdx.x * 256 + threadIdx.x;  // < 368640
  int ci = e % 40;   int r = e / 40;
  int ocl = r % 128; r /= 128;
  int s = r % 36;    int oh = r / 36;
  int chh = s / 18;
  int t2  = s % 18;
  int tap = t2 >> 1, kc = t2 & 1;
  unsigned short v = 0;
  if (ci < 32) {
    int oc = oh * 128 + ocl;
    int c  = chh * 64 + kc * 32 + ci;
    v = f2bf(w[(size_t)(oc * 128 + c) * 9 + tap]);
  }
  wpack[e] = v;
}

// ---------------------------------------------------------------------------
// Prepack projection weights (straight f32->bf16 cast, K-contiguous already).
// h_w 192x64 @0, m_w 128x64 @12288, z1_w 64x128 @20480, z2_w 192x128 @28672
// ---------------------------------------------------------------------------
__global__ __launch_bounds__(256) void wproj_kernel(
    const float* __restrict__ h_w, const float* __restrict__ m_w,
    const float* __restrict__ z1_w, const float* __restrict__ z2_w,
    unsigned short* __restrict__ wp)
{
  int e = blockIdx.x * 256 + threadIdx.x;
  if (e >= 53248) return;
  float v;
  if (e < 12288)       v = h_w[e];
  else if (e < 20480)  v = m_w[e - 12288];
  else if (e < 28672)  v = z1_w[e - 20480];
  else                 v = z2_w[e - 28672];
  wp[e] = f2bf(v);
}

// ---------------------------------------------------------------------------
// Conv 3x3 SAME via bf16 MFMA (16x16x32), 9-shifted-taps, full K=1152.
// ---------------------------------------------------------------------------
__global__ __launch_bounds__(256) void conv3_mfma_kernel(
    const float* __restrict__ x,    // [B][T][64][1024]
    const float* __restrict__ ihb,  // [B][64][1024]
    const unsigned short* __restrict__ wpack,
    const float* __restrict__ bias, // [256]
    float* __restrict__ gates, int t)
{
  int ptile = blockIdx.x;
  int b     = blockIdx.y;
  int oh    = blockIdx.z;

  __shared__ __align__(16) unsigned short img[4 * 34 * 136];   // 36992 B
  __shared__ __align__(16) unsigned short wbuf[2][128 * 40];   // 2 x 10240 B

  int tid  = threadIdx.x;
  int lane = tid & 63;
  int wv   = tid >> 6;
  int mrow = wv >> 1, ncol = wv & 1;
  int y0 = ptile * 2;

  for (int i = tid; i < 4 * 34 * 136 / 2; i += 256) ((unsigned*)img)[i] = 0u;
  __syncthreads();

  const float* xsrc = x + (size_t)(b * 8 + t) * 65536;
  const float* hsrc = ihb + (size_t)b * 65536;
#pragma unroll
  for (int i = 0; i < 16; ++i) {
    int u = tid + i * 256;
    int ch = u >> 5;
    int v5 = u & 31;
    int row = v5 >> 3;
    int col4 = (v5 & 7) * 4;
    int gy = y0 - 1 + row;
    if (gy >= 0 && gy < 32) {
      const float* src = (ch < 64) ? (xsrc + (size_t)ch * 1024)
                                   : (hsrc + (size_t)(ch - 64) * 1024);
      float4 f = *(const float4*)(src + gy * 32 + col4);
      int base = (row * 34 + col4 + 1) * 136 + ch;
      img[base]       = f2bf(f.x);
      img[base + 136] = f2bf(f.y);
      img[base + 272] = f2bf(f.z);
      img[base + 408] = f2bf(f.w);
    }
  }

  const unsigned* wsl = (const unsigned*)wpack + (size_t)oh * 36 * 2560;
  unsigned* wb32 = (unsigned*)&wbuf[0][0];
#pragma unroll
  for (int k2 = 0; k2 < 10; ++k2)
    wb32[tid + k2 * 256] = wsl[tid + k2 * 256];
  __syncthreads();

  int aoff = (mrow * 64 + (lane & 15)) * 40 + (lane >> 4) * 8;
  int pb[2];
#pragma unroll
  for (int nf = 0; nf < 2; ++nf) {
    int pp = ncol * 32 + nf * 16 + (lane & 15);
    int rr = pp >> 5, cc = pp & 31;
    pb[nf] = (rr * 34 + cc) * 136 + (lane >> 4) * 8;
  }

  f32x4 acc[4][2] = {};
  unsigned wreg[10];

#pragma unroll
  for (int s = 0; s < 36; ++s) {
    int cur = s & 1;
    if (s < 35) {
      const unsigned* nsl = wsl + (s + 1) * 2560;
#pragma unroll
      for (int k2 = 0; k2 < 10; ++k2) wreg[k2] = nsl[tid + k2 * 256];
    }
    int chh = s / 18;
    int t2  = s % 18;
    int tap = t2 >> 1, kc = t2 & 1;
    int dy = tap / 3, dx = tap % 3;
    int toff = (dy * 34 + dx) * 136 + chh * 64 + kc * 32;

    bf16x8 a[4], bb[2];
#pragma unroll
    for (int mf = 0; mf < 4; ++mf)
      a[mf] = *(const bf16x8*)&wbuf[cur][aoff + mf * 640];
#pragma unroll
    for (int nf = 0; nf < 2; ++nf)
      bb[nf] = *(const bf16x8*)&img[pb[nf] + toff];
#pragma unroll
    for (int mf = 0; mf < 4; ++mf)
#pragma unroll
      for (int nf = 0; nf < 2; ++nf)
        acc[mf][nf] = __builtin_amdgcn_mfma_f32_16x16x32_bf16(
            a[mf], bb[nf], acc[mf][nf], 0, 0, 0);

    if (s < 35) {
      unsigned* dst = (unsigned*)&wbuf[0][0] + (1 - cur) * 2560;
#pragma unroll
      for (int k2 = 0; k2 < 10; ++k2) dst[tid + k2 * 256] = wreg[k2];
    }
    __syncthreads();
  }

  int orow_base = oh * 128 + mrow * 64 + (lane >> 4) * 4;
  int pcol = ptile * 64 + ncol * 32 + (lane & 15);
  float* gout = gates + (size_t)b * 262144;
#pragma unroll
  for (int mf = 0; mf < 4; ++mf)
#pragma unroll
    for (int nf = 0; nf < 2; ++nf)
#pragma unroll
      for (int r = 0; r < 4; ++r) {
        int oc_ = orow_base + mf * 16 + r;
        gout[(size_t)oc_ * 1024 + pcol + nf * 16] = acc[mf][nf][r] + bias[oc_];
      }
}

// ---------------------------------------------------------------------------
// GroupNorm stats
// ---------------------------------------------------------------------------
__global__ __launch_bounds__(256) void gnstats_kernel(
    const float* __restrict__ g, float* __restrict__ st)
{
  int grp = blockIdx.x; int b = blockIdx.y;
  const float* p0 = g + (size_t)b * 262144 + (size_t)grp * 32768;
  float s = 0.0f, q = 0.0f;
  for (int i = threadIdx.x; i < 8192; i += 256) {
    float4 a = *(const float4*)(p0 + (size_t)i * 4);
    s += a.x + a.y + a.z + a.w;
    q += a.x * a.x + a.y * a.y + a.z * a.z + a.w * a.w;
  }
#pragma unroll
  for (int off = 32; off > 0; off >>= 1) {
    s += __shfl_down(s, off);
    q += __shfl_down(q, off);
  }
  __shared__ float ss[4], qq[4];
  int wid = threadIdx.x >> 6;
  if ((threadIdx.x & 63) == 0) { ss[wid] = s; qq[wid] = q; }
  __syncthreads();
  if (threadIdx.x == 0) {
    float S = ss[0] + ss[1] + ss[2] + ss[3];
    float Q = qq[0] + qq[1] + qq[2] + qq[3];
    float mu = S / 32768.0f;
    float var = Q / 32768.0f - mu * mu;
    st[(b * 8 + grp) * 2]     = mu;
    st[(b * 8 + grp) * 2 + 1] = rsqrtf(var + 1e-5f);
  }
}

// ---------------------------------------------------------------------------
// GN apply + LSTM gates.
// ---------------------------------------------------------------------------
__global__ __launch_bounds__(256) void gnlstm_kernel(
    const float* __restrict__ g,
    const float* __restrict__ st, const float* __restrict__ gn_g,
    const float* __restrict__ gn_b, float* __restrict__ ic,
    float* __restrict__ cat2, float* __restrict__ out)
{
  int c = blockIdx.x; int b = blockIdx.y;
  int px = threadIdx.x * 4;
  size_t base = (size_t)b * 262144 + (size_t)c * 1024 + px;

  float4 vi4 = *(const float4*)(g + base);
  float4 vf4 = *(const float4*)(g + base + 65536);
  float4 vc4 = *(const float4*)(g + base + 131072);
  float4 vo4 = *(const float4*)(g + base + 196608);

  int ch0 = c, ch1 = 64 + c, ch2 = 128 + c, ch3 = 192 + c;
  float mu, is;
  mu = st[(b * 8 + (ch0 >> 5)) * 2]; is = st[(b * 8 + (ch0 >> 5)) * 2 + 1];
  float ga0 = gn_g[ch0] * is, bb0 = gn_b[ch0] - mu * ga0;
  mu = st[(b * 8 + (ch1 >> 5)) * 2]; is = st[(b * 8 + (ch1 >> 5)) * 2 + 1];
  float ga1 = gn_g[ch1] * is, bb1 = gn_b[ch1] - mu * ga1;
  mu = st[(b * 8 + (ch2 >> 5)) * 2]; is = st[(b * 8 + (ch2 >> 5)) * 2 + 1];
  float ga2 = gn_g[ch2] * is, bb2 = gn_b[ch2] - mu * ga2;
  mu = st[(b * 8 + (ch3 >> 5)) * 2]; is = st[(b * 8 + (ch3 >> 5)) * 2 + 1];
  float ga3 = gn_g[ch3] * is, bb3 = gn_b[ch3] - mu * ga3;

  size_t sb = (size_t)b * 65536 + (size_t)c * 1024 + px;
  float4 icv = *(const float4*)(ic + sb);
  float* vip = (float*)&vi4; float* vfp = (float*)&vf4;
  float* vcp = (float*)&vc4; float* vop = (float*)&vo4;
  float* icp = (float*)&icv;
  float4 ocv, ohv;
  float* ocp = (float*)&ocv; float* ohp = (float*)&ohv;
#pragma unroll
  for (int j = 0; j < 4; ++j) {
    float ing = sigm(vip[j] * ga0 + bb0);
    float fg  = sigm(vfp[j] * ga1 + bb1);
    float cg  = tanhf(vcp[j] * ga2 + bb2);
    float og  = sigm(vop[j] * ga3 + bb3);
    float oc  = icp[j] * fg + ing * cg;
    ocp[j] = oc;
    ohp[j] = og * tanhf(oc);
  }
  *(float4*)(ic + sb) = ocv;
  *(float4*)(out + 4718592 + sb) = ocv;  // ocT tail
  *(float4*)(cat2 + (size_t)b * 131072 + (size_t)(64 + c) * 1024 + px) = ohv;
}

// ---------------------------------------------------------------------------
// MFMA GEMM: C[b][m][n] = sum_k Wp[m][k] * (X[b][k][n] (+X2)) + bias[m]
// Wp prepacked bf16 [M][K] (K in {64,128}). Block = 64m x 64n tile, 4 waves
// (wave w = 16-row m-frag). X^T staged to LDS bf16 [64 n][K+8].
// grid (16 nt, M/64 mt, 8 b).
// ---------------------------------------------------------------------------
__global__ __launch_bounds__(256) void gemm_mfma_kernel(
    const unsigned short* __restrict__ Wp, const float* __restrict__ X,
    const float* __restrict__ X2, const float* __restrict__ bias,
    float* __restrict__ C, int K, int xbs, int cbs)
{
  int nt = blockIdx.x, mt = blockIdx.y, b = blockIdx.z;
  __shared__ __align__(16) unsigned short Xs[64 * 136];  // max K=128
  int tid = threadIdx.x, lane = tid & 63, w = tid >> 6;
  int n0 = nt * 64;
  int kstride = K + 8;
  const float* Xb  = X + (size_t)b * xbs;
  const float* X2b = X2 ? (X2 + (size_t)b * xbs) : nullptr;

  // stage X^T: Xs[nl][c], paired-c u32 stores.
  // elements = 64 n x K/2 u32 = 32K -> iters = 32K/256 = K/8   (R7 bug: K/16)
  int niter = K / 8;
  for (int i = 0; i < niter; ++i) {
    int u = tid + i * 256;
    int c2 = u >> 6, nl = u & 63;
    float f0 = Xb[(size_t)(2 * c2) * 1024 + n0 + nl];
    float f1 = Xb[(size_t)(2 * c2 + 1) * 1024 + n0 + nl];
    if (X2b) {
      f0 += X2b[(size_t)(2 * c2) * 1024 + n0 + nl];
      f1 += X2b[(size_t)(2 * c2 + 1) * 1024 + n0 + nl];
    }
    ((unsigned*)Xs)[nl * (kstride / 2) + c2] = pk2(f0, f1);
  }
  __syncthreads();

  // A-frags straight from global (bf16, K-contiguous)
  int mrow = mt * 64 + w * 16 + (lane & 15);
  bf16x8 ka[4];
  int nks = K / 32;
  for (int ks = 0; ks < nks; ++ks)
    ka[ks] = *(const bf16x8*)&Wp[(size_t)mrow * K + ks * 32 + (lane >> 4) * 8];

  f32x4 acc[4] = {};
#pragma unroll
  for (int nf = 0; nf < 4; ++nf) {
    for (int ks = 0; ks < nks; ++ks) {
      bf16x8 bx = *(const bf16x8*)&Xs[(nf * 16 + (lane & 15)) * kstride +
                                      ks * 32 + (lane >> 4) * 8];
      acc[nf] = __builtin_amdgcn_mfma_f32_16x16x32_bf16(ka[ks], bx, acc[nf], 0, 0, 0);
    }
  }

  // epilogue: D col = n (lane&15), row = m ((lane>>4)*4 + r)
  float* Cb = C + (size_t)b * cbs;
#pragma unroll
  for (int nf = 0; nf < 4; ++nf)
#pragma unroll
    for (int r = 0; r < 4; ++r) {
      int m = mt * 64 + w * 16 + (lane >> 4) * 4 + r;
      Cb[(size_t)m * 1024 + n0 + nf * 16 + (lane & 15)] = acc[nf][r] + bias[m];
    }
}

// ---------------------------------------------------------------------------
// Attention pass 1 (MFMA): per-row-n max & sumexp of S = Q^T K over m-half.
// grid (16 nt, 4 = att*2+mh, 8 b), 256 thr (4 waves = 16-row n-stripes).
// stats out: [b][att][mh][{M,D}][1024]
// ---------------------------------------------------------------------------
__global__ __launch_bounds__(256) void att_stats_kernel(
    const float* __restrict__ qkv, const float* __restrict__ mkv,
    float* __restrict__ stats)
{
  int nt = blockIdx.x;
  int att = blockIdx.y >> 1, mh = blockIdx.y & 1;
  int b = blockIdx.z;
  const float* Qb = qkv + (size_t)b * 196608;
  const float* Kb = att ? (mkv + (size_t)b * 131072)
                        : (qkv + (size_t)b * 196608 + 65536);
  __shared__ __align__(16) unsigned short Qs[64 * 72];
  __shared__ __align__(16) unsigned short Ks[64 * 72];
  int tid = threadIdx.x, lane = tid & 63, w = tid >> 6;
  int n0 = nt * 64;

  // stage Q^T tile: Qs[nl][c]
#pragma unroll
  for (int i = 0; i < 8; ++i) {
    int u = tid + i * 256;
    int c2 = u >> 6, nl = u & 63;
    float f0 = Qb[(size_t)(2 * c2) * 1024 + n0 + nl];
    float f1 = Qb[(size_t)(2 * c2 + 1) * 1024 + n0 + nl];
    ((unsigned*)Qs)[nl * 36 + c2] = pk2(f0, f1);
  }
  __syncthreads();
  bf16x8 qa0 = *(const bf16x8*)&Qs[(w * 16 + (lane & 15)) * 72 + (lane >> 4) * 8];
  bf16x8 qa1 = *(const bf16x8*)&Qs[(w * 16 + (lane & 15)) * 72 + 32 + (lane >> 4) * 8];

  float M[4] = {-3.0e38f, -3.0e38f, -3.0e38f, -3.0e38f};
  float Dsum[4] = {0.f, 0.f, 0.f, 0.f};

  for (int mt = mh * 8; mt < mh * 8 + 8; ++mt) {
    __syncthreads();
#pragma unroll
    for (int i = 0; i < 8; ++i) {
      int u = tid + i * 256;
      int c2 = u >> 6, ml = u & 63;
      float f0 = Kb[(size_t)(2 * c2) * 1024 + mt * 64 + ml];
      float f1 = Kb[(size_t)(2 * c2 + 1) * 1024 + mt * 64 + ml];
      ((unsigned*)Ks)[ml * 36 + c2] = pk2(f0, f1);
    }
    __syncthreads();
    f32x4 s[4];
#pragma unroll
    for (int mf = 0; mf < 4; ++mf) {
      bf16x8 b0 = *(const bf16x8*)&Ks[(mf * 16 + (lane & 15)) * 72 + (lane >> 4) * 8];
      bf16x8 b1 = *(const bf16x8*)&Ks[(mf * 16 + (lane & 15)) * 72 + 32 + (lane >> 4) * 8];
      f32x4 tacc = {};
      tacc = __builtin_amdgcn_mfma_f32_16x16x32_bf16(qa0, b0, tacc, 0, 0, 0);
      tacc = __builtin_amdgcn_mfma_f32_16x16x32_bf16(qa1, b1, tacc, 0, 0, 0);
      s[mf] = tacc;
    }
#pragma unroll
    for (int r = 0; r < 4; ++r) {
      float v0 = s[0][r], v1 = s[1][r], v2 = s[2][r], v3 = s[3][r];
      float mx = fmaxf(fmaxf(v0, v1), fmaxf(v2, v3));
      float nm = fmaxf(M[r], mx);
      Dsum[r] = Dsum[r] * __expf(M[r] - nm) +
                __expf(v0 - nm) + __expf(v1 - nm) +
                __expf(v2 - nm) + __expf(v3 - nm);
      M[r] = nm;
    }
  }
#pragma unroll
  for (int off = 1; off < 16; off <<= 1) {
#pragma unroll
    for (int r = 0; r < 4; ++r) {
      float Mo = __shfl_xor(M[r], off);
      float Do = __shfl_xor(Dsum[r], off);
      float nm = fmaxf(M[r], Mo);
      Dsum[r] = Dsum[r] * __expf(M[r] - nm) + Do * __expf(Mo - nm);
      M[r] = nm;
    }
  }
  if ((lane & 15) == 0) {
    float* stb = stats + (size_t)(((b * 2 + att) * 2 + mh) * 2) * 1024;
#pragma unroll
    for (int r = 0; r < 4; ++r) {
      int n = n0 + w * 16 + (lane >> 4) * 4 + r;
      stb[n] = M[r];
      stb[1024 + n] = Dsum[r];
    }
  }
}

// ---------------------------------------------------------------------------
// Attention pass 2 (MFMA): Z[c][m] = sum_n (V[c][n]*rD[n]) * exp(S[n][m]-M[n])
// grid (16 mt, 4 = att*2+nh, 8 b). Partial Z per n-half -> zc0/zc1 (summed in
// z1 gemm). Merges the two m-half stats online.
// ---------------------------------------------------------------------------
__global__ __launch_bounds__(256) void att_z_kernel(
    const float* __restrict__ qkv, const float* __restrict__ mkv,
    const float* __restrict__ stats, float* __restrict__ zc0,
    float* __restrict__ zc1)
{
  int mt = blockIdx.x;
  int att = blockIdx.y >> 1, nh = blockIdx.y & 1;
  int b = blockIdx.z;
  const float* Qb = qkv + (size_t)b * 196608;
  const float* Kb = att ? (mkv + (size_t)b * 131072)
                        : (qkv + (size_t)b * 196608 + 65536);
  const float* Vb = att ? (mkv + (size_t)b * 131072 + 65536)
                        : (qkv + (size_t)b * 196608 + 131072);
  const float* stb = stats + (size_t)(b * 2 + att) * 4096;

  __shared__ __align__(16) unsigned short Ks[64 * 72];
  __shared__ __align__(16) unsigned short Qs[64 * 72];
  __shared__ __align__(16) unsigned short Vs[64 * 72];
  __shared__ __align__(16) unsigned short Ps[64 * 72];
  __shared__ float Mn[64];
  __shared__ float Rn[64];

  int tid = threadIdx.x, lane = tid & 63, w = tid >> 6;
  int m0 = mt * 64;

  // stage K^T tile once: Ks[ml][c]
#pragma unroll
  for (int i = 0; i < 8; ++i) {
    int u = tid + i * 256;
    int c2 = u >> 6, ml = u & 63;
    float f0 = Kb[(size_t)(2 * c2) * 1024 + m0 + ml];
    float f1 = Kb[(size_t)(2 * c2 + 1) * 1024 + m0 + ml];
    ((unsigned*)Ks)[ml * 36 + c2] = pk2(f0, f1);
  }
  __syncthreads();
  bf16x8 bk[4][2];
#pragma unroll
  for (int mf = 0; mf < 4; ++mf) {
    bk[mf][0] = *(const bf16x8*)&Ks[(mf * 16 + (lane & 15)) * 72 + (lane >> 4) * 8];
    bk[mf][1] = *(const bf16x8*)&Ks[(mf * 16 + (lane & 15)) * 72 + 32 + (lane >> 4) * 8];
  }

  f32x4 zacc[4] = {};

  for (int ntb = nh * 8; ntb < nh * 8 + 8; ++ntb) {
    int n0 = ntb * 64;
    __syncthreads();  // previous iteration's reads complete
    // merge two m-half stats for these 64 n rows
    if (tid < 64) {
      int n = n0 + tid;
      float M0 = stb[n],        D0 = stb[1024 + n];
      float M1 = stb[2048 + n], D1 = stb[3072 + n];
      float Mm = fmaxf(M0, M1);
      float Dm = D0 * __expf(M0 - Mm) + D1 * __expf(M1 - Mm);
      Mn[tid] = Mm;
      Rn[tid] = 1.0f / Dm;
    }
    // stage Q^T: Qs[nl][c]
#pragma unroll
    for (int i = 0; i < 8; ++i) {
      int u = tid + i * 256;
      int c2 = u >> 6, nl = u & 63;
      float f0 = Qb[(size_t)(2 * c2) * 1024 + n0 + nl];
      float f1 = Qb[(size_t)(2 * c2 + 1) * 1024 + n0 + nl];
      ((unsigned*)Qs)[nl * 36 + c2] = pk2(f0, f1);
    }
    __syncthreads();
    // stage Vd[c][n] = V[c][n]*rD[n]
#pragma unroll
    for (int i = 0; i < 4; ++i) {
      int u = tid + i * 256;
      int c = u >> 4, n4 = (u & 15) * 4;
      float4 v = *(const float4*)(Vb + (size_t)c * 1024 + n0 + n4);
      unsigned* dst = (unsigned*)&Vs[c * 72 + n4];
      dst[0] = pk2(v.x * Rn[n4], v.y * Rn[n4 + 1]);
      dst[1] = pk2(v.z * Rn[n4 + 2], v.w * Rn[n4 + 3]);
    }

    // S = Q^T K, P = exp(S - M[n]) -> Ps^T
    bf16x8 qa0 = *(const bf16x8*)&Qs[(w * 16 + (lane & 15)) * 72 + (lane >> 4) * 8];
    bf16x8 qa1 = *(const bf16x8*)&Qs[(w * 16 + (lane & 15)) * 72 + 32 + (lane >> 4) * 8];
    float mr[4];
#pragma unroll
    for (int r = 0; r < 4; ++r) mr[r] = Mn[w * 16 + (lane >> 4) * 4 + r];
#pragma unroll
    for (int mf = 0; mf < 4; ++mf) {
      f32x4 tacc = {};
      tacc = __builtin_amdgcn_mfma_f32_16x16x32_bf16(qa0, bk[mf][0], tacc, 0, 0, 0);
      tacc = __builtin_amdgcn_mfma_f32_16x16x32_bf16(qa1, bk[mf][1], tacc, 0, 0, 0);
      unsigned* dst = (unsigned*)&Ps[(mf * 16 + (lane & 15)) * 72 +
                                     w * 16 + (lane >> 4) * 4];
      dst[0] = pk2(__expf(tacc[0] - mr[0]), __expf(tacc[1] - mr[1]));
      dst[1] = pk2(__expf(tacc[2] - mr[2]), __expf(tacc[3] - mr[3]));
    }
    __syncthreads();

    // Z += Vd x P
    bf16x8 va0 = *(const bf16x8*)&Vs[(w * 16 + (lane & 15)) * 72 + (lane >> 4) * 8];
    bf16x8 va1 = *(const bf16x8*)&Vs[(w * 16 + (lane & 15)) * 72 + 32 + (lane >> 4) * 8];
#pragma unroll
    for (int mf = 0; mf < 4; ++mf) {
      bf16x8 p0 = *(const bf16x8*)&Ps[(mf * 16 + (lane & 15)) * 72 + (lane >> 4) * 8];
      bf16x8 p1 = *(const bf16x8*)&Ps[(mf * 16 + (lane & 15)) * 72 + 32 + (lane >> 4) * 8];
      zacc[mf] = __builtin_amdgcn_mfma_f32_16x16x32_bf16(va0, p0, zacc[mf], 0, 0, 0);
      zacc[mf] = __builtin_amdgcn_mfma_f32_16x16x32_bf16(va1, p1, zacc[mf], 0, 0, 0);
    }
  }

  float* zb = (nh ? zc1 : zc0) + (size_t)b * 131072 + (size_t)att * 65536;
#pragma unroll
  for (int mf = 0; mf < 4; ++mf)
#pragma unroll
    for (int r = 0; r < 4; ++r) {
      int c = w * 16 + (lane >> 4) * 4 + r;
      zb[(size_t)c * 1024 + m0 + mf * 16 + (lane & 15)] = zacc[mf][r];
    }
}

// ---------------------------------------------------------------------------
// SAM output gating.
// ---------------------------------------------------------------------------
__global__ __launch_bounds__(256) void sam_kernel(
    const float* __restrict__ g2, float* __restrict__ im,
    float* __restrict__ ih, float* __restrict__ out, int t)
{
  int c = blockIdx.x; int b = blockIdx.y;
  int px = threadIdx.x * 4;
  size_t gb = (size_t)b * 196608 + (size_t)c * 1024 + px;
  float4 vo4 = *(const float4*)(g2 + gb);
  float4 vg4 = *(const float4*)(g2 + gb + 65536);
  float4 vi4 = *(const float4*)(g2 + gb + 131072);
  size_t sb = (size_t)b * 65536 + (size_t)c * 1024 + px;
  float4 vm4 = *(const float4*)(im + sb);
  float* vop = (float*)&vo4; float* vgp = (float*)&vg4;
  float* vip = (float*)&vi4; float* vmp = (float*)&vm4;
  float4 om4, oh4;
  float* omp = (float*)&om4; float* ohp = (float*)&oh4;
#pragma unroll
  for (int j = 0; j < 4; ++j) {
    float ig = sigm(vip[j]);
    float om = tanhf(vgp[j]) * ig + (1.0f - ig) * vmp[j];
    omp[j] = om;
    ohp[j] = sigm(vop[j]) * om;
  }
  *(float4*)(im + sb) = om4;
  *(float4*)(ih + sb) = oh4;
  *(float4*)(out + ((size_t)(b * 8 + t) * 64 + c) * 1024 + px) = oh4;
  *(float4*)(out + 4194304 + sb) = oh4;  // ohT tail
  *(float4*)(out + 5242880 + sb) = om4;  // imT tail
}

// ---------------------------------------------------------------------------
extern "C" void kernel_launch(void* const* d_in, const int* in_sizes, int n_in,
                              void* d_out, int out_size, void* d_ws,
                              size_t ws_size, hipStream_t stream)
{
  const float* x      = (const float*)d_in[0];
  const float* conv_w = (const float*)d_in[1];
  const float* conv_b = (const float*)d_in[2];
  const float* gn_g   = (const float*)d_in[3];
  const float* gn_b   = (const float*)d_in[4];
  const float* h_w    = (const float*)d_in[5];
  const float* h_b    = (const float*)d_in[6];
  const float* m_w    = (const float*)d_in[7];
  const float* m_b    = (const float*)d_in[8];
  const float* z1_w   = (const float*)d_in[9];
  const float* z1_b   = (const float*)d_in[10];
  const float* z2_w   = (const float*)d_in[11];
  const float* z2_b   = (const float*)d_in[12];
  float* out = (float*)d_out;
  float* ws  = (float*)d_ws;

  float* ic     = ws;
  float* ih     = ws + 524288;
  float* im     = ws + 1048576;
  float* gates  = ws + 1572864;
  float* gnst   = ws + 3670016;
  float* qkv    = ws + 3670272;
  float* mkv    = ws + 5243136;
  float* stats  = ws + 6291712;
  float* cat2   = ws + 6357248;
  float* zc0    = ws + 7405824;
  unsigned short* wpack = (unsigned short*)(ws + 8454400);
  unsigned short* wproj = (unsigned short*)(ws + 8638720);
  float* zc1    = ws + 8665344;
  float* g2     = gates;              // reuse after gnlstm

  const unsigned short* hp  = wproj;
  const unsigned short* mp  = wproj + 12288;
  const unsigned short* z1p = wproj + 20480;
  const unsigned short* z2p = wproj + 28672;

  // zero initial states ih, ic, im (contiguous)
  hipMemsetAsync(ic, 0, (size_t)3 * 524288 * sizeof(float), stream);
  // prepack weights
  wprep_kernel<<<dim3(1440), 256, 0, stream>>>(conv_w, wpack);
  wproj_kernel<<<dim3(208), 256, 0, stream>>>(h_w, m_w, z1_w, z2_w, wproj);

  for (int t = 0; t < 8; ++t) {
    conv3_mfma_kernel<<<dim3(16, 8, 2), 256, 0, stream>>>(
        x, ih, wpack, conv_b, gates, t);
    gnstats_kernel<<<dim3(8, 8), 256, 0, stream>>>(gates, gnst);
    gnlstm_kernel<<<dim3(64, 8), 256, 0, stream>>>(gates, gnst, gn_g,
                                                   gn_b, ic, cat2, out);
    // projections: h_qkv = h_w @ oh (cat2 rows 64-127); m_kv = m_w @ im
    gemm_mfma_kernel<<<dim3(16, 3, 8), 256, 0, stream>>>(
        hp, cat2 + 65536, nullptr, h_b, qkv, 64, 131072, 196608);
    gemm_mfma_kernel<<<dim3(16, 2, 8), 256, 0, stream>>>(
        mp, im, nullptr, m_b, mkv, 64, 65536, 131072);
    att_stats_kernel<<<dim3(16, 4, 8), 256, 0, stream>>>(qkv, mkv, stats);
    att_z_kernel<<<dim3(16, 4, 8), 256, 0, stream>>>(qkv, mkv, stats, zc0, zc1);
    // z1: Zc = z1_w @ (zc0 + zc1) -> cat2 top half
    gemm_mfma_kernel<<<dim3(16, 1, 8), 256, 0, stream>>>(
        z1p, zc0, zc1, z1_b, cat2, 128, 131072, 131072);
    // z2: gates2 = z2_w @ cat2
    gemm_mfma_kernel<<<dim3(16, 3, 8), 256, 0, stream>>>(
        z2p, cat2, nullptr, z2_b, g2, 128, 131072, 196608);
    sam_kernel<<<dim3(64, 8), 256, 0, stream>>>(g2, im, ih, out, t);
  }
}

// Round 9
// 1098.135 us; speedup vs baseline: 2.1792x; 2.1792x over previous
//
#include <hip/hip_runtime.h>
#include <math.h>

// Problem constants: B=8, T=8, CIN=64, FN=64, H=W=32, HW=1024, GROUPS=8
// ws layout (floats):
//  ic     @ 0        (524288)
//  ih     @ 524288   (524288)
//  im     @ 1048576  (524288)
//  gates  @ 1572864  (2097152)   [conv out; reused as g2 (z2 out) later]
//  gnstat @ 3670016  (256)
//  qkv    @ 3670272  (1572864)   [B][192][1024]: Q 0-63, Kh 64-127, Vh 128-191
//  mkv    @ 5243136  (1048576)   [B][128][1024]: Km 0-63, Vm 64-127
//  stats  @ 6291712  (65536)     [b][att][mh][{M,D}][1024]
//  cat2   @ 6357248  (1048576)   [B][128][1024]: Zc rows 0-63, oh rows 64-127
//  zc0    @ 7405824  (1048576)   [B][128][1024] partial Z (n-half 0)
//  wpack  @ 8454400  (184320)    MFMA-packed conv weights (bf16)
//  wproj  @ 8638720  (26624)     bf16 proj weights: h@0 m@12288 z1@20480 z2@28672
//  zc1    @ 8665344  (1048576)   partial Z (n-half 1)
// total 9713920 floats = 38.9 MB

#define DEV __device__ __forceinline__

DEV float sigm(float x) { return 1.0f / (1.0f + __expf(-x)); }

DEV unsigned short f2bf(float f) {
  union { float f; unsigned u; } v; v.f = f;
  unsigned r = v.u + 0x7FFF + ((v.u >> 16) & 1);  // RNE
  return (unsigned short)(r >> 16);
}

DEV unsigned pk2(float a, float b) {
  return (unsigned)f2bf(a) | ((unsigned)f2bf(b) << 16);
}

typedef float f32x4 __attribute__((ext_vector_type(4)));
typedef short bf16x8 __attribute__((ext_vector_type(8)));

// ---------------------------------------------------------------------------
// Prepack conv weights to bf16 MFMA layout:
// wpack[oh 2][s 36][ocl 128][ci 40]   (ci 0..31 real, 32..39 = 0)
// ---------------------------------------------------------------------------
__global__ __launch_bounds__(256) void wprep_kernel(
    const float* __restrict__ w, unsigned short* __restrict__ wpack)
{
  int e = blockIdx.x * 256 + threadIdx.x;  // < 368640
  int ci = e % 40;   int r = e / 40;
  int ocl = r % 128; r /= 128;
  int s = r % 36;    int oh = r / 36;
  int chh = s / 18;
  int t2  = s % 18;
  int tap = t2 >> 1, kc = t2 & 1;
  unsigned short v = 0;
  if (ci < 32) {
    int oc = oh * 128 + ocl;
    int c  = chh * 64 + kc * 32 + ci;
    v = f2bf(w[(size_t)(oc * 128 + c) * 9 + tap]);
  }
  wpack[e] = v;
}

// ---------------------------------------------------------------------------
// Prepack projection weights (straight f32->bf16 cast, K-contiguous already).
// h_w 192x64 @0, m_w 128x64 @12288, z1_w 64x128 @20480, z2_w 192x128 @28672
// ---------------------------------------------------------------------------
__global__ __launch_bounds__(256) void wproj_kernel(
    const float* __restrict__ h_w, const float* __restrict__ m_w,
    const float* __restrict__ z1_w, const float* __restrict__ z2_w,
    unsigned short* __restrict__ wp)
{
  int e = blockIdx.x * 256 + threadIdx.x;
  if (e >= 53248) return;
  float v;
  if (e < 12288)       v = h_w[e];
  else if (e < 20480)  v = m_w[e - 12288];
  else if (e < 28672)  v = z1_w[e - 20480];
  else                 v = z2_w[e - 28672];
  wp[e] = f2bf(v);
}

// ---------------------------------------------------------------------------
// Conv 3x3 SAME via bf16 MFMA (16x16x32), 9-shifted-taps, full K=1152.
// ---------------------------------------------------------------------------
__global__ __launch_bounds__(256) void conv3_mfma_kernel(
    const float* __restrict__ x,    // [B][T][64][1024]
    const float* __restrict__ ihb,  // [B][64][1024]
    const unsigned short* __restrict__ wpack,
    const float* __restrict__ bias, // [256]
    float* __restrict__ gates, int t)
{
  int ptile = blockIdx.x;
  int b     = blockIdx.y;
  int oh    = blockIdx.z;

  __shared__ __align__(16) unsigned short img[4 * 34 * 136];   // 36992 B
  __shared__ __align__(16) unsigned short wbuf[2][128 * 40];   // 2 x 10240 B

  int tid  = threadIdx.x;
  int lane = tid & 63;
  int wv   = tid >> 6;
  int mrow = wv >> 1, ncol = wv & 1;
  int y0 = ptile * 2;

  for (int i = tid; i < 4 * 34 * 136 / 2; i += 256) ((unsigned*)img)[i] = 0u;
  __syncthreads();

  const float* xsrc = x + (size_t)(b * 8 + t) * 65536;
  const float* hsrc = ihb + (size_t)b * 65536;
#pragma unroll
  for (int i = 0; i < 16; ++i) {
    int u = tid + i * 256;
    int ch = u >> 5;
    int v5 = u & 31;
    int row = v5 >> 3;
    int col4 = (v5 & 7) * 4;
    int gy = y0 - 1 + row;
    if (gy >= 0 && gy < 32) {
      const float* src = (ch < 64) ? (xsrc + (size_t)ch * 1024)
                                   : (hsrc + (size_t)(ch - 64) * 1024);
      float4 f = *(const float4*)(src + gy * 32 + col4);
      int base = (row * 34 + col4 + 1) * 136 + ch;
      img[base]       = f2bf(f.x);
      img[base + 136] = f2bf(f.y);
      img[base + 272] = f2bf(f.z);
      img[base + 408] = f2bf(f.w);
    }
  }

  const unsigned* wsl = (const unsigned*)wpack + (size_t)oh * 36 * 2560;
  unsigned* wb32 = (unsigned*)&wbuf[0][0];
#pragma unroll
  for (int k2 = 0; k2 < 10; ++k2)
    wb32[tid + k2 * 256] = wsl[tid + k2 * 256];
  __syncthreads();

  int aoff = (mrow * 64 + (lane & 15)) * 40 + (lane >> 4) * 8;
  int pb[2];
#pragma unroll
  for (int nf = 0; nf < 2; ++nf) {
    int pp = ncol * 32 + nf * 16 + (lane & 15);
    int rr = pp >> 5, cc = pp & 31;
    pb[nf] = (rr * 34 + cc) * 136 + (lane >> 4) * 8;
  }

  f32x4 acc[4][2] = {};
  unsigned wreg[10];

#pragma unroll
  for (int s = 0; s < 36; ++s) {
    int cur = s & 1;
    if (s < 35) {
      const unsigned* nsl = wsl + (s + 1) * 2560;
#pragma unroll
      for (int k2 = 0; k2 < 10; ++k2) wreg[k2] = nsl[tid + k2 * 256];
    }
    int chh = s / 18;
    int t2  = s % 18;
    int tap = t2 >> 1, kc = t2 & 1;
    int dy = tap / 3, dx = tap % 3;
    int toff = (dy * 34 + dx) * 136 + chh * 64 + kc * 32;

    bf16x8 a[4], bb[2];
#pragma unroll
    for (int mf = 0; mf < 4; ++mf)
      a[mf] = *(const bf16x8*)&wbuf[cur][aoff + mf * 640];
#pragma unroll
    for (int nf = 0; nf < 2; ++nf)
      bb[nf] = *(const bf16x8*)&img[pb[nf] + toff];
#pragma unroll
    for (int mf = 0; mf < 4; ++mf)
#pragma unroll
      for (int nf = 0; nf < 2; ++nf)
        acc[mf][nf] = __builtin_amdgcn_mfma_f32_16x16x32_bf16(
            a[mf], bb[nf], acc[mf][nf], 0, 0, 0);

    if (s < 35) {
      unsigned* dst = (unsigned*)&wbuf[0][0] + (1 - cur) * 2560;
#pragma unroll
      for (int k2 = 0; k2 < 10; ++k2) dst[tid + k2 * 256] = wreg[k2];
    }
    __syncthreads();
  }

  int orow_base = oh * 128 + mrow * 64 + (lane >> 4) * 4;
  int pcol = ptile * 64 + ncol * 32 + (lane & 15);
  float* gout = gates + (size_t)b * 262144;
#pragma unroll
  for (int mf = 0; mf < 4; ++mf)
#pragma unroll
    for (int nf = 0; nf < 2; ++nf)
#pragma unroll
      for (int r = 0; r < 4; ++r) {
        int oc_ = orow_base + mf * 16 + r;
        gout[(size_t)oc_ * 1024 + pcol + nf * 16] = acc[mf][nf][r] + bias[oc_];
      }
}

// ---------------------------------------------------------------------------
// GroupNorm stats
// ---------------------------------------------------------------------------
__global__ __launch_bounds__(256) void gnstats_kernel(
    const float* __restrict__ g, float* __restrict__ st)
{
  int grp = blockIdx.x; int b = blockIdx.y;
  const float* p0 = g + (size_t)b * 262144 + (size_t)grp * 32768;
  float s = 0.0f, q = 0.0f;
  for (int i = threadIdx.x; i < 8192; i += 256) {
    float4 a = *(const float4*)(p0 + (size_t)i * 4);
    s += a.x + a.y + a.z + a.w;
    q += a.x * a.x + a.y * a.y + a.z * a.z + a.w * a.w;
  }
#pragma unroll
  for (int off = 32; off > 0; off >>= 1) {
    s += __shfl_down(s, off);
    q += __shfl_down(q, off);
  }
  __shared__ float ss[4], qq[4];
  int wid = threadIdx.x >> 6;
  if ((threadIdx.x & 63) == 0) { ss[wid] = s; qq[wid] = q; }
  __syncthreads();
  if (threadIdx.x == 0) {
    float S = ss[0] + ss[1] + ss[2] + ss[3];
    float Q = qq[0] + qq[1] + qq[2] + qq[3];
    float mu = S / 32768.0f;
    float var = Q / 32768.0f - mu * mu;
    st[(b * 8 + grp) * 2]     = mu;
    st[(b * 8 + grp) * 2 + 1] = rsqrtf(var + 1e-5f);
  }
}

// ---------------------------------------------------------------------------
// GN apply + LSTM gates.
// ---------------------------------------------------------------------------
__global__ __launch_bounds__(256) void gnlstm_kernel(
    const float* __restrict__ g,
    const float* __restrict__ st, const float* __restrict__ gn_g,
    const float* __restrict__ gn_b, float* __restrict__ ic,
    float* __restrict__ cat2, float* __restrict__ out)
{
  int c = blockIdx.x; int b = blockIdx.y;
  int px = threadIdx.x * 4;
  size_t base = (size_t)b * 262144 + (size_t)c * 1024 + px;

  float4 vi4 = *(const float4*)(g + base);
  float4 vf4 = *(const float4*)(g + base + 65536);
  float4 vc4 = *(const float4*)(g + base + 131072);
  float4 vo4 = *(const float4*)(g + base + 196608);

  int ch0 = c, ch1 = 64 + c, ch2 = 128 + c, ch3 = 192 + c;
  float mu, is;
  mu = st[(b * 8 + (ch0 >> 5)) * 2]; is = st[(b * 8 + (ch0 >> 5)) * 2 + 1];
  float ga0 = gn_g[ch0] * is, bb0 = gn_b[ch0] - mu * ga0;
  mu = st[(b * 8 + (ch1 >> 5)) * 2]; is = st[(b * 8 + (ch1 >> 5)) * 2 + 1];
  float ga1 = gn_g[ch1] * is, bb1 = gn_b[ch1] - mu * ga1;
  mu = st[(b * 8 + (ch2 >> 5)) * 2]; is = st[(b * 8 + (ch2 >> 5)) * 2 + 1];
  float ga2 = gn_g[ch2] * is, bb2 = gn_b[ch2] - mu * ga2;
  mu = st[(b * 8 + (ch3 >> 5)) * 2]; is = st[(b * 8 + (ch3 >> 5)) * 2 + 1];
  float ga3 = gn_g[ch3] * is, bb3 = gn_b[ch3] - mu * ga3;

  size_t sb = (size_t)b * 65536 + (size_t)c * 1024 + px;
  float4 icv = *(const float4*)(ic + sb);
  float* vip = (float*)&vi4; float* vfp = (float*)&vf4;
  float* vcp = (float*)&vc4; float* vop = (float*)&vo4;
  float* icp = (float*)&icv;
  float4 ocv, ohv;
  float* ocp = (float*)&ocv; float* ohp = (float*)&ohv;
#pragma unroll
  for (int j = 0; j < 4; ++j) {
    float ing = sigm(vip[j] * ga0 + bb0);
    float fg  = sigm(vfp[j] * ga1 + bb1);
    float cg  = tanhf(vcp[j] * ga2 + bb2);
    float og  = sigm(vop[j] * ga3 + bb3);
    float oc  = icp[j] * fg + ing * cg;
    ocp[j] = oc;
    ohp[j] = og * tanhf(oc);
  }
  *(float4*)(ic + sb) = ocv;
  *(float4*)(out + 4718592 + sb) = ocv;  // ocT tail
  *(float4*)(cat2 + (size_t)b * 131072 + (size_t)(64 + c) * 1024 + px) = ohv;
}

// ---------------------------------------------------------------------------
// MFMA GEMM: C[b][m][n] = sum_k Wp[m][k] * (X[b][k][n] (+X2)) + bias[m]
// K is a TEMPLATE param (R8 bug: runtime K -> runtime-indexed frag arrays ->
// scratch spill, VGPR=32, 84 us/dispatch). Block = 64m x 64n, 4 waves.
// ---------------------------------------------------------------------------
template <int K>
__global__ __launch_bounds__(256) void gemm_mfma_kernel(
    const unsigned short* __restrict__ Wp, const float* __restrict__ X,
    const float* __restrict__ X2, const float* __restrict__ bias,
    float* __restrict__ C, int xbs, int cbs)
{
  constexpr int KS = K + 8;      // LDS row stride (shorts)
  constexpr int NKS = K / 32;    // MFMA k-steps
  int nt = blockIdx.x, mt = blockIdx.y, b = blockIdx.z;
  __shared__ __align__(16) unsigned short Xs[64 * KS];
  int tid = threadIdx.x, lane = tid & 63, w = tid >> 6;
  int n0 = nt * 64;
  const float* Xb  = X + (size_t)b * xbs;
  const float* X2b = X2 ? (X2 + (size_t)b * xbs) : nullptr;

  // stage X^T: Xs[nl][c], paired-c u32 stores. iters = 64*(K/2)/256 = K/8
#pragma unroll
  for (int i = 0; i < K / 8; ++i) {
    int u = tid + i * 256;
    int c2 = u >> 6, nl = u & 63;
    float f0 = Xb[(size_t)(2 * c2) * 1024 + n0 + nl];
    float f1 = Xb[(size_t)(2 * c2 + 1) * 1024 + n0 + nl];
    if (X2b) {
      f0 += X2b[(size_t)(2 * c2) * 1024 + n0 + nl];
      f1 += X2b[(size_t)(2 * c2 + 1) * 1024 + n0 + nl];
    }
    ((unsigned*)Xs)[nl * (KS / 2) + c2] = pk2(f0, f1);
  }
  __syncthreads();

  // A-frags straight from global (bf16, K-contiguous)
  int mrow = mt * 64 + w * 16 + (lane & 15);
  bf16x8 ka[NKS];
#pragma unroll
  for (int ks = 0; ks < NKS; ++ks)
    ka[ks] = *(const bf16x8*)&Wp[(size_t)mrow * K + ks * 32 + (lane >> 4) * 8];

  f32x4 acc[4] = {};
#pragma unroll
  for (int nf = 0; nf < 4; ++nf) {
#pragma unroll
    for (int ks = 0; ks < NKS; ++ks) {
      bf16x8 bx = *(const bf16x8*)&Xs[(nf * 16 + (lane & 15)) * KS +
                                      ks * 32 + (lane >> 4) * 8];
      acc[nf] = __builtin_amdgcn_mfma_f32_16x16x32_bf16(ka[ks], bx, acc[nf], 0, 0, 0);
    }
  }

  // epilogue: D col = n (lane&15), row = m ((lane>>4)*4 + r)
  float* Cb = C + (size_t)b * cbs;
#pragma unroll
  for (int nf = 0; nf < 4; ++nf)
#pragma unroll
    for (int r = 0; r < 4; ++r) {
      int m = mt * 64 + w * 16 + (lane >> 4) * 4 + r;
      Cb[(size_t)m * 1024 + n0 + nf * 16 + (lane & 15)] = acc[nf][r] + bias[m];
    }
}

// ---------------------------------------------------------------------------
// Attention pass 1 (MFMA): per-row-n max & sumexp of S = Q^T K over m-half.
// grid (16 nt, 4 = att*2+mh, 8 b), 256 thr (4 waves = 16-row n-stripes).
// stats out: [b][att][mh][{M,D}][1024]
// ---------------------------------------------------------------------------
__global__ __launch_bounds__(256) void att_stats_kernel(
    const float* __restrict__ qkv, const float* __restrict__ mkv,
    float* __restrict__ stats)
{
  int nt = blockIdx.x;
  int att = blockIdx.y >> 1, mh = blockIdx.y & 1;
  int b = blockIdx.z;
  const float* Qb = qkv + (size_t)b * 196608;
  const float* Kb = att ? (mkv + (size_t)b * 131072)
                        : (qkv + (size_t)b * 196608 + 65536);
  __shared__ __align__(16) unsigned short Qs[64 * 72];
  __shared__ __align__(16) unsigned short Ks[64 * 72];
  int tid = threadIdx.x, lane = tid & 63, w = tid >> 6;
  int n0 = nt * 64;

  // stage Q^T tile: Qs[nl][c]
#pragma unroll
  for (int i = 0; i < 8; ++i) {
    int u = tid + i * 256;
    int c2 = u >> 6, nl = u & 63;
    float f0 = Qb[(size_t)(2 * c2) * 1024 + n0 + nl];
    float f1 = Qb[(size_t)(2 * c2 + 1) * 1024 + n0 + nl];
    ((unsigned*)Qs)[nl * 36 + c2] = pk2(f0, f1);
  }
  __syncthreads();
  bf16x8 qa0 = *(const bf16x8*)&Qs[(w * 16 + (lane & 15)) * 72 + (lane >> 4) * 8];
  bf16x8 qa1 = *(const bf16x8*)&Qs[(w * 16 + (lane & 15)) * 72 + 32 + (lane >> 4) * 8];

  float M[4] = {-3.0e38f, -3.0e38f, -3.0e38f, -3.0e38f};
  float Dsum[4] = {0.f, 0.f, 0.f, 0.f};

  for (int mt = mh * 8; mt < mh * 8 + 8; ++mt) {
    __syncthreads();
#pragma unroll
    for (int i = 0; i < 8; ++i) {
      int u = tid + i * 256;
      int c2 = u >> 6, ml = u & 63;
      float f0 = Kb[(size_t)(2 * c2) * 1024 + mt * 64 + ml];
      float f1 = Kb[(size_t)(2 * c2 + 1) * 1024 + mt * 64 + ml];
      ((unsigned*)Ks)[ml * 36 + c2] = pk2(f0, f1);
    }
    __syncthreads();
    f32x4 s[4];
#pragma unroll
    for (int mf = 0; mf < 4; ++mf) {
      bf16x8 b0 = *(const bf16x8*)&Ks[(mf * 16 + (lane & 15)) * 72 + (lane >> 4) * 8];
      bf16x8 b1 = *(const bf16x8*)&Ks[(mf * 16 + (lane & 15)) * 72 + 32 + (lane >> 4) * 8];
      f32x4 tacc = {};
      tacc = __builtin_amdgcn_mfma_f32_16x16x32_bf16(qa0, b0, tacc, 0, 0, 0);
      tacc = __builtin_amdgcn_mfma_f32_16x16x32_bf16(qa1, b1, tacc, 0, 0, 0);
      s[mf] = tacc;
    }
#pragma unroll
    for (int r = 0; r < 4; ++r) {
      float v0 = s[0][r], v1 = s[1][r], v2 = s[2][r], v3 = s[3][r];
      float mx = fmaxf(fmaxf(v0, v1), fmaxf(v2, v3));
      float nm = fmaxf(M[r], mx);
      Dsum[r] = Dsum[r] * __expf(M[r] - nm) +
                __expf(v0 - nm) + __expf(v1 - nm) +
                __expf(v2 - nm) + __expf(v3 - nm);
      M[r] = nm;
    }
  }
#pragma unroll
  for (int off = 1; off < 16; off <<= 1) {
#pragma unroll
    for (int r = 0; r < 4; ++r) {
      float Mo = __shfl_xor(M[r], off);
      float Do = __shfl_xor(Dsum[r], off);
      float nm = fmaxf(M[r], Mo);
      Dsum[r] = Dsum[r] * __expf(M[r] - nm) + Do * __expf(Mo - nm);
      M[r] = nm;
    }
  }
  if ((lane & 15) == 0) {
    float* stb = stats + (size_t)(((b * 2 + att) * 2 + mh) * 2) * 1024;
#pragma unroll
    for (int r = 0; r < 4; ++r) {
      int n = n0 + w * 16 + (lane >> 4) * 4 + r;
      stb[n] = M[r];
      stb[1024 + n] = Dsum[r];
    }
  }
}

// ---------------------------------------------------------------------------
// Attention pass 2 (MFMA): Z[c][m] = sum_n (V[c][n]*rD[n]) * exp(S[n][m]-M[n])
// grid (16 mt, 4 = att*2+nh, 8 b). Partial Z per n-half -> zc0/zc1 (summed in
// z1 gemm). Merges the two m-half stats online.
// ---------------------------------------------------------------------------
__global__ __launch_bounds__(256) void att_z_kernel(
    const float* __restrict__ qkv, const float* __restrict__ mkv,
    const float* __restrict__ stats, float* __restrict__ zc0,
    float* __restrict__ zc1)
{
  int mt = blockIdx.x;
  int att = blockIdx.y >> 1, nh = blockIdx.y & 1;
  int b = blockIdx.z;
  const float* Qb = qkv + (size_t)b * 196608;
  const float* Kb = att ? (mkv + (size_t)b * 131072)
                        : (qkv + (size_t)b * 196608 + 65536);
  const float* Vb = att ? (mkv + (size_t)b * 131072 + 65536)
                        : (qkv + (size_t)b * 196608 + 131072);
  const float* stb = stats + (size_t)(b * 2 + att) * 4096;

  __shared__ __align__(16) unsigned short Ks[64 * 72];
  __shared__ __align__(16) unsigned short Qs[64 * 72];
  __shared__ __align__(16) unsigned short Vs[64 * 72];
  __shared__ __align__(16) unsigned short Ps[64 * 72];
  __shared__ float Mn[64];
  __shared__ float Rn[64];

  int tid = threadIdx.x, lane = tid & 63, w = tid >> 6;
  int m0 = mt * 64;

  // stage K^T tile once: Ks[ml][c]
#pragma unroll
  for (int i = 0; i < 8; ++i) {
    int u = tid + i * 256;
    int c2 = u >> 6, ml = u & 63;
    float f0 = Kb[(size_t)(2 * c2) * 1024 + m0 + ml];
    float f1 = Kb[(size_t)(2 * c2 + 1) * 1024 + m0 + ml];
    ((unsigned*)Ks)[ml * 36 + c2] = pk2(f0, f1);
  }
  __syncthreads();
  bf16x8 bk[4][2];
#pragma unroll
  for (int mf = 0; mf < 4; ++mf) {
    bk[mf][0] = *(const bf16x8*)&Ks[(mf * 16 + (lane & 15)) * 72 + (lane >> 4) * 8];
    bk[mf][1] = *(const bf16x8*)&Ks[(mf * 16 + (lane & 15)) * 72 + 32 + (lane >> 4) * 8];
  }

  f32x4 zacc[4] = {};

  for (int ntb = nh * 8; ntb < nh * 8 + 8; ++ntb) {
    int n0 = ntb * 64;
    __syncthreads();  // previous iteration's reads complete
    // merge two m-half stats for these 64 n rows
    if (tid < 64) {
      int n = n0 + tid;
      float M0 = stb[n],        D0 = stb[1024 + n];
      float M1 = stb[2048 + n], D1 = stb[3072 + n];
      float Mm = fmaxf(M0, M1);
      float Dm = D0 * __expf(M0 - Mm) + D1 * __expf(M1 - Mm);
      Mn[tid] = Mm;
      Rn[tid] = 1.0f / Dm;
    }
    // stage Q^T: Qs[nl][c]
#pragma unroll
    for (int i = 0; i < 8; ++i) {
      int u = tid + i * 256;
      int c2 = u >> 6, nl = u & 63;
      float f0 = Qb[(size_t)(2 * c2) * 1024 + n0 + nl];
      float f1 = Qb[(size_t)(2 * c2 + 1) * 1024 + n0 + nl];
      ((unsigned*)Qs)[nl * 36 + c2] = pk2(f0, f1);
    }
    __syncthreads();
    // stage Vd[c][n] = V[c][n]*rD[n]
#pragma unroll
    for (int i = 0; i < 4; ++i) {
      int u = tid + i * 256;
      int c = u >> 4, n4 = (u & 15) * 4;
      float4 v = *(const float4*)(Vb + (size_t)c * 1024 + n0 + n4);
      unsigned* dst = (unsigned*)&Vs[c * 72 + n4];
      dst[0] = pk2(v.x * Rn[n4], v.y * Rn[n4 + 1]);
      dst[1] = pk2(v.z * Rn[n4 + 2], v.w * Rn[n4 + 3]);
    }

    // S = Q^T K, P = exp(S - M[n]) -> Ps^T
    bf16x8 qa0 = *(const bf16x8*)&Qs[(w * 16 + (lane & 15)) * 72 + (lane >> 4) * 8];
    bf16x8 qa1 = *(const bf16x8*)&Qs[(w * 16 + (lane & 15)) * 72 + 32 + (lane >> 4) * 8];
    float mr[4];
#pragma unroll
    for (int r = 0; r < 4; ++r) mr[r] = Mn[w * 16 + (lane >> 4) * 4 + r];
#pragma unroll
    for (int mf = 0; mf < 4; ++mf) {
      f32x4 tacc = {};
      tacc = __builtin_amdgcn_mfma_f32_16x16x32_bf16(qa0, bk[mf][0], tacc, 0, 0, 0);
      tacc = __builtin_amdgcn_mfma_f32_16x16x32_bf16(qa1, bk[mf][1], tacc, 0, 0, 0);
      unsigned* dst = (unsigned*)&Ps[(mf * 16 + (lane & 15)) * 72 +
                                     w * 16 + (lane >> 4) * 4];
      dst[0] = pk2(__expf(tacc[0] - mr[0]), __expf(tacc[1] - mr[1]));
      dst[1] = pk2(__expf(tacc[2] - mr[2]), __expf(tacc[3] - mr[3]));
    }
    __syncthreads();

    // Z += Vd x P
    bf16x8 va0 = *(const bf16x8*)&Vs[(w * 16 + (lane & 15)) * 72 + (lane >> 4) * 8];
    bf16x8 va1 = *(const bf16x8*)&Vs[(w * 16 + (lane & 15)) * 72 + 32 + (lane >> 4) * 8];
#pragma unroll
    for (int mf = 0; mf < 4; ++mf) {
      bf16x8 p0 = *(const bf16x8*)&Ps[(mf * 16 + (lane & 15)) * 72 + (lane >> 4) * 8];
      bf16x8 p1 = *(const bf16x8*)&Ps[(mf * 16 + (lane & 15)) * 72 + 32 + (lane >> 4) * 8];
      zacc[mf] = __builtin_amdgcn_mfma_f32_16x16x32_bf16(va0, p0, zacc[mf], 0, 0, 0);
      zacc[mf] = __builtin_amdgcn_mfma_f32_16x16x32_bf16(va1, p1, zacc[mf], 0, 0, 0);
    }
  }

  float* zb = (nh ? zc1 : zc0) + (size_t)b * 131072 + (size_t)att * 65536;
#pragma unroll
  for (int mf = 0; mf < 4; ++mf)
#pragma unroll
    for (int r = 0; r < 4; ++r) {
      int c = w * 16 + (lane >> 4) * 4 + r;
      zb[(size_t)c * 1024 + m0 + mf * 16 + (lane & 15)] = zacc[mf][r];
    }
}

// ---------------------------------------------------------------------------
// SAM output gating.
// ---------------------------------------------------------------------------
__global__ __launch_bounds__(256) void sam_kernel(
    const float* __restrict__ g2, float* __restrict__ im,
    float* __restrict__ ih, float* __restrict__ out, int t)
{
  int c = blockIdx.x; int b = blockIdx.y;
  int px = threadIdx.x * 4;
  size_t gb = (size_t)b * 196608 + (size_t)c * 1024 + px;
  float4 vo4 = *(const float4*)(g2 + gb);
  float4 vg4 = *(const float4*)(g2 + gb + 65536);
  float4 vi4 = *(const float4*)(g2 + gb + 131072);
  size_t sb = (size_t)b * 65536 + (size_t)c * 1024 + px;
  float4 vm4 = *(const float4*)(im + sb);
  float* vop = (float*)&vo4; float* vgp = (float*)&vg4;
  float* vip = (float*)&vi4; float* vmp = (float*)&vm4;
  float4 om4, oh4;
  float* omp = (float*)&om4; float* ohp = (float*)&oh4;
#pragma unroll
  for (int j = 0; j < 4; ++j) {
    float ig = sigm(vip[j]);
    float om = tanhf(vgp[j]) * ig + (1.0f - ig) * vmp[j];
    omp[j] = om;
    ohp[j] = sigm(vop[j]) * om;
  }
  *(float4*)(im + sb) = om4;
  *(float4*)(ih + sb) = oh4;
  *(float4*)(out + ((size_t)(b * 8 + t) * 64 + c) * 1024 + px) = oh4;
  *(float4*)(out + 4194304 + sb) = oh4;  // ohT tail
  *(float4*)(out + 5242880 + sb) = om4;  // imT tail
}

// ---------------------------------------------------------------------------
extern "C" void kernel_launch(void* const* d_in, const int* in_sizes, int n_in,
                              void* d_out, int out_size, void* d_ws,
                              size_t ws_size, hipStream_t stream)
{
  const float* x      = (const float*)d_in[0];
  const float* conv_w = (const float*)d_in[1];
  const float* conv_b = (const float*)d_in[2];
  const float* gn_g   = (const float*)d_in[3];
  const float* gn_b   = (const float*)d_in[4];
  const float* h_w    = (const float*)d_in[5];
  const float* h_b    = (const float*)d_in[6];
  const float* m_w    = (const float*)d_in[7];
  const float* m_b    = (const float*)d_in[8];
  const float* z1_w   = (const float*)d_in[9];
  const float* z1_b   = (const float*)d_in[10];
  const float* z2_w   = (const float*)d_in[11];
  const float* z2_b   = (const float*)d_in[12];
  float* out = (float*)d_out;
  float* ws  = (float*)d_ws;

  float* ic     = ws;
  float* ih     = ws + 524288;
  float* im     = ws + 1048576;
  float* gates  = ws + 1572864;
  float* gnst   = ws + 3670016;
  float* qkv    = ws + 3670272;
  float* mkv    = ws + 5243136;
  float* stats  = ws + 6291712;
  float* cat2   = ws + 6357248;
  float* zc0    = ws + 7405824;
  unsigned short* wpack = (unsigned short*)(ws + 8454400);
  unsigned short* wproj = (unsigned short*)(ws + 8638720);
  float* zc1    = ws + 8665344;
  float* g2     = gates;              // reuse after gnlstm

  const unsigned short* hp  = wproj;
  const unsigned short* mp  = wproj + 12288;
  const unsigned short* z1p = wproj + 20480;
  const unsigned short* z2p = wproj + 28672;

  // zero initial states ih, ic, im (contiguous)
  hipMemsetAsync(ic, 0, (size_t)3 * 524288 * sizeof(float), stream);
  // prepack weights
  wprep_kernel<<<dim3(1440), 256, 0, stream>>>(conv_w, wpack);
  wproj_kernel<<<dim3(208), 256, 0, stream>>>(h_w, m_w, z1_w, z2_w, wproj);

  for (int t = 0; t < 8; ++t) {
    conv3_mfma_kernel<<<dim3(16, 8, 2), 256, 0, stream>>>(
        x, ih, wpack, conv_b, gates, t);
    gnstats_kernel<<<dim3(8, 8), 256, 0, stream>>>(gates, gnst);
    gnlstm_kernel<<<dim3(64, 8), 256, 0, stream>>>(gates, gnst, gn_g,
                                                   gn_b, ic, cat2, out);
    // projections: h_qkv = h_w @ oh (cat2 rows 64-127); m_kv = m_w @ im
    gemm_mfma_kernel<64><<<dim3(16, 3, 8), 256, 0, stream>>>(
        hp, cat2 + 65536, nullptr, h_b, qkv, 131072, 196608);
    gemm_mfma_kernel<64><<<dim3(16, 2, 8), 256, 0, stream>>>(
        mp, im, nullptr, m_b, mkv, 65536, 131072);
    att_stats_kernel<<<dim3(16, 4, 8), 256, 0, stream>>>(qkv, mkv, stats);
    att_z_kernel<<<dim3(16, 4, 8), 256, 0, stream>>>(qkv, mkv, stats, zc0, zc1);
    // z1: Zc = z1_w @ (zc0 + zc1) -> cat2 top half
    gemm_mfma_kernel<128><<<dim3(16, 1, 8), 256, 0, stream>>>(
        z1p, zc0, zc1, z1_b, cat2, 131072, 131072);
    // z2: gates2 = z2_w @ cat2
    gemm_mfma_kernel<128><<<dim3(16, 3, 8), 256, 0, stream>>>(
        z2p, cat2, nullptr, z2_b, g2, 131072, 196608);
    sam_kernel<<<dim3(64, 8), 256, 0, stream>>>(g2, im, ih, out, t);
  }
}

// Round 11
// 1075.903 us; speedup vs baseline: 2.2242x; 1.0207x over previous
//
#include <hip/hip_runtime.h>
#include <math.h>

// Problem constants: B=8, T=8, CIN=64, FN=64, H=W=32, HW=1024, GROUPS=8
// ws layout (floats):
//  ic     @ 0         (524288)
//  ih     @ 524288    (524288)
//  im     @ 1048576   (524288)
//  gates  @ 1572864   (2097152)  [conv out; reused as g2 (z2 out) later]
//  gnstat @ 3670016   (256)
//  qkv    @ 3670272   (1572864)  [B][192][1024] f32: Q, Kh, Vh
//  mkv    @ 5243136   (1048576)  [B][128][1024] f32: Km, Vm
//  stats  @ 6291712   (65536)    [b][att][mh][{M,D}][1024]
//  cat2   @ 6357248   (1048576)  [B][128][1024]: Zc rows 0-63, oh rows 64-127
//  stats2 @ 7405824   (32768)    [b][att][{M,1/D}][1024]
//  wpack  @ 7438592   (184320)   MFMA-packed conv weights (bf16)
//  wproj  @ 7622912   (26624)    bf16 proj weights: h@0 m@12288 z1@20480 z2@28672
//  apack  @ 7649536   (1310720)  bf16 attn pack: 5 slabs x 524288 shorts
//                                [Qt, Kht, Kmt, Vh, Vm]; Qt/Kt = [b][1024][64]
//  zc     @ 8960256   (4194304)  4 partial-Z slabs x [B][128][1024]
// total 13154560 floats = 52.6 MB (ws ~268 MB per harness fill — safe)

#define DEV __device__ __forceinline__

DEV float sigm(float x) { return 1.0f / (1.0f + __expf(-x)); }

DEV unsigned short f2bf(float f) {
  union { float f; unsigned u; } v; v.f = f;
  unsigned r = v.u + 0x7FFF + ((v.u >> 16) & 1);  // RNE
  return (unsigned short)(r >> 16);
}

DEV unsigned pk2(float a, float b) {
  return (unsigned)f2bf(a) | ((unsigned)f2bf(b) << 16);
}

typedef float f32x4 __attribute__((ext_vector_type(4)));
typedef short bf16x8 __attribute__((ext_vector_type(8)));

// ---------------------------------------------------------------------------
// Prepack conv weights to bf16 MFMA layout:
// wpack[oh 2][s 36][ocl 128][ci 40]   (ci 0..31 real, 32..39 = 0)
// ---------------------------------------------------------------------------
__global__ __launch_bounds__(256) void wprep_kernel(
    const float* __restrict__ w, unsigned short* __restrict__ wpack)
{
  int e = blockIdx.x * 256 + threadIdx.x;  // < 368640
  int ci = e % 40;   int r = e / 40;
  int ocl = r % 128; r /= 128;
  int s = r % 36;    int oh = r / 36;
  int chh = s / 18;
  int t2  = s % 18;
  int tap = t2 >> 1, kc = t2 & 1;
  unsigned short v = 0;
  if (ci < 32) {
    int oc = oh * 128 + ocl;
    int c  = chh * 64 + kc * 32 + ci;
    v = f2bf(w[(size_t)(oc * 128 + c) * 9 + tap]);
  }
  wpack[e] = v;
}

// ---------------------------------------------------------------------------
// Prepack projection weights (straight f32->bf16 cast, K-contiguous already).
// ---------------------------------------------------------------------------
__global__ __launch_bounds__(256) void wproj_kernel(
    const float* __restrict__ h_w, const float* __restrict__ m_w,
    const float* __restrict__ z1_w, const float* __restrict__ z2_w,
    unsigned short* __restrict__ wp)
{
  int e = blockIdx.x * 256 + threadIdx.x;
  if (e >= 53248) return;
  float v;
  if (e < 12288)       v = h_w[e];
  else if (e < 20480)  v = m_w[e - 12288];
  else if (e < 28672)  v = z1_w[e - 20480];
  else                 v = z2_w[e - 28672];
  wp[e] = f2bf(v);
}

// ---------------------------------------------------------------------------
// Conv 3x3 SAME via bf16 MFMA (16x16x32), 9-shifted-taps, full K=1152.
// ---------------------------------------------------------------------------
__global__ __launch_bounds__(256) void conv3_mfma_kernel(
    const float* __restrict__ x,    // [B][T][64][1024]
    const float* __restrict__ ihb,  // [B][64][1024]
    const unsigned short* __restrict__ wpack,
    const float* __restrict__ bias, // [256]
    float* __restrict__ gates, int t)
{
  int ptile = blockIdx.x;
  int b     = blockIdx.y;
  int oh    = blockIdx.z;

  __shared__ __align__(16) unsigned short img[4 * 34 * 136];   // 36992 B
  __shared__ __align__(16) unsigned short wbuf[2][128 * 40];   // 2 x 10240 B

  int tid  = threadIdx.x;
  int lane = tid & 63;
  int wv   = tid >> 6;
  int mrow = wv >> 1, ncol = wv & 1;
  int y0 = ptile * 2;

  for (int i = tid; i < 4 * 34 * 136 / 2; i += 256) ((unsigned*)img)[i] = 0u;
  __syncthreads();

  const float* xsrc = x + (size_t)(b * 8 + t) * 65536;
  const float* hsrc = ihb + (size_t)b * 65536;
#pragma unroll
  for (int i = 0; i < 16; ++i) {
    int u = tid + i * 256;
    int ch = u >> 5;
    int v5 = u & 31;
    int row = v5 >> 3;
    int col4 = (v5 & 7) * 4;
    int gy = y0 - 1 + row;
    if (gy >= 0 && gy < 32) {
      const float* src = (ch < 64) ? (xsrc + (size_t)ch * 1024)
                                   : (hsrc + (size_t)(ch - 64) * 1024);
      float4 f = *(const float4*)(src + gy * 32 + col4);
      int base = (row * 34 + col4 + 1) * 136 + ch;
      img[base]       = f2bf(f.x);
      img[base + 136] = f2bf(f.y);
      img[base + 272] = f2bf(f.z);
      img[base + 408] = f2bf(f.w);
    }
  }

  const unsigned* wsl = (const unsigned*)wpack + (size_t)oh * 36 * 2560;
  unsigned* wb32 = (unsigned*)&wbuf[0][0];
#pragma unroll
  for (int k2 = 0; k2 < 10; ++k2)
    wb32[tid + k2 * 256] = wsl[tid + k2 * 256];
  __syncthreads();

  int aoff = (mrow * 64 + (lane & 15)) * 40 + (lane >> 4) * 8;
  int pb[2];
#pragma unroll
  for (int nf = 0; nf < 2; ++nf) {
    int pp = ncol * 32 + nf * 16 + (lane & 15);
    int rr = pp >> 5, cc = pp & 31;
    pb[nf] = (rr * 34 + cc) * 136 + (lane >> 4) * 8;
  }

  f32x4 acc[4][2] = {};
  unsigned wreg[10];

#pragma unroll
  for (int s = 0; s < 36; ++s) {
    int cur = s & 1;
    if (s < 35) {
      const unsigned* nsl = wsl + (s + 1) * 2560;
#pragma unroll
      for (int k2 = 0; k2 < 10; ++k2) wreg[k2] = nsl[tid + k2 * 256];
    }
    int chh = s / 18;
    int t2  = s % 18;
    int tap = t2 >> 1, kc = t2 & 1;
    int dy = tap / 3, dx = tap % 3;
    int toff = (dy * 34 + dx) * 136 + chh * 64 + kc * 32;

    bf16x8 a[4], bb[2];
#pragma unroll
    for (int mf = 0; mf < 4; ++mf)
      a[mf] = *(const bf16x8*)&wbuf[cur][aoff + mf * 640];
#pragma unroll
    for (int nf = 0; nf < 2; ++nf)
      bb[nf] = *(const bf16x8*)&img[pb[nf] + toff];
#pragma unroll
    for (int mf = 0; mf < 4; ++mf)
#pragma unroll
      for (int nf = 0; nf < 2; ++nf)
        acc[mf][nf] = __builtin_amdgcn_mfma_f32_16x16x32_bf16(
            a[mf], bb[nf], acc[mf][nf], 0, 0, 0);

    if (s < 35) {
      unsigned* dst = (unsigned*)&wbuf[0][0] + (1 - cur) * 2560;
#pragma unroll
      for (int k2 = 0; k2 < 10; ++k2) dst[tid + k2 * 256] = wreg[k2];
    }
    __syncthreads();
  }

  int orow_base = oh * 128 + mrow * 64 + (lane >> 4) * 4;
  int pcol = ptile * 64 + ncol * 32 + (lane & 15);
  float* gout = gates + (size_t)b * 262144;
#pragma unroll
  for (int mf = 0; mf < 4; ++mf)
#pragma unroll
    for (int nf = 0; nf < 2; ++nf)
#pragma unroll
      for (int r = 0; r < 4; ++r) {
        int oc_ = orow_base + mf * 16 + r;
        gout[(size_t)oc_ * 1024 + pcol + nf * 16] = acc[mf][nf][r] + bias[oc_];
      }
}

// ---------------------------------------------------------------------------
// GroupNorm stats
// ---------------------------------------------------------------------------
__global__ __launch_bounds__(256) void gnstats_kernel(
    const float* __restrict__ g, float* __restrict__ st)
{
  int grp = blockIdx.x; int b = blockIdx.y;
  const float* p0 = g + (size_t)b * 262144 + (size_t)grp * 32768;
  float s = 0.0f, q = 0.0f;
  for (int i = threadIdx.x; i < 8192; i += 256) {
    float4 a = *(const float4*)(p0 + (size_t)i * 4);
    s += a.x + a.y + a.z + a.w;
    q += a.x * a.x + a.y * a.y + a.z * a.z + a.w * a.w;
  }
#pragma unroll
  for (int off = 32; off > 0; off >>= 1) {
    s += __shfl_down(s, off);
    q += __shfl_down(q, off);
  }
  __shared__ float ss[4], qq[4];
  int wid = threadIdx.x >> 6;
  if ((threadIdx.x & 63) == 0) { ss[wid] = s; qq[wid] = q; }
  __syncthreads();
  if (threadIdx.x == 0) {
    float S = ss[0] + ss[1] + ss[2] + ss[3];
    float Q = qq[0] + qq[1] + qq[2] + qq[3];
    float mu = S / 32768.0f;
    float var = Q / 32768.0f - mu * mu;
    st[(b * 8 + grp) * 2]     = mu;
    st[(b * 8 + grp) * 2 + 1] = rsqrtf(var + 1e-5f);
  }
}

// ---------------------------------------------------------------------------
// GN apply + LSTM gates.
// ---------------------------------------------------------------------------
__global__ __launch_bounds__(256) void gnlstm_kernel(
    const float* __restrict__ g,
    const float* __restrict__ st, const float* __restrict__ gn_g,
    const float* __restrict__ gn_b, float* __restrict__ ic,
    float* __restrict__ cat2, float* __restrict__ out)
{
  int c = blockIdx.x; int b = blockIdx.y;
  int px = threadIdx.x * 4;
  size_t base = (size_t)b * 262144 + (size_t)c * 1024 + px;

  float4 vi4 = *(const float4*)(g + base);
  float4 vf4 = *(const float4*)(g + base + 65536);
  float4 vc4 = *(const float4*)(g + base + 131072);
  float4 vo4 = *(const float4*)(g + base + 196608);

  int ch0 = c, ch1 = 64 + c, ch2 = 128 + c, ch3 = 192 + c;
  float mu, is;
  mu = st[(b * 8 + (ch0 >> 5)) * 2]; is = st[(b * 8 + (ch0 >> 5)) * 2 + 1];
  float ga0 = gn_g[ch0] * is, bb0 = gn_b[ch0] - mu * ga0;
  mu = st[(b * 8 + (ch1 >> 5)) * 2]; is = st[(b * 8 + (ch1 >> 5)) * 2 + 1];
  float ga1 = gn_g[ch1] * is, bb1 = gn_b[ch1] - mu * ga1;
  mu = st[(b * 8 + (ch2 >> 5)) * 2]; is = st[(b * 8 + (ch2 >> 5)) * 2 + 1];
  float ga2 = gn_g[ch2] * is, bb2 = gn_b[ch2] - mu * ga2;
  mu = st[(b * 8 + (ch3 >> 5)) * 2]; is = st[(b * 8 + (ch3 >> 5)) * 2 + 1];
  float ga3 = gn_g[ch3] * is, bb3 = gn_b[ch3] - mu * ga3;

  size_t sb = (size_t)b * 65536 + (size_t)c * 1024 + px;
  float4 icv = *(const float4*)(ic + sb);
  float* vip = (float*)&vi4; float* vfp = (float*)&vf4;
  float* vcp = (float*)&vc4; float* vop = (float*)&vo4;
  float* icp = (float*)&icv;
  float4 ocv, ohv;
  float* ocp = (float*)&ocv; float* ohp = (float*)&ohv;
#pragma unroll
  for (int j = 0; j < 4; ++j) {
    float ing = sigm(vip[j] * ga0 + bb0);
    float fg  = sigm(vfp[j] * ga1 + bb1);
    float cg  = tanhf(vcp[j] * ga2 + bb2);
    float og  = sigm(vop[j] * ga3 + bb3);
    float oc  = icp[j] * fg + ing * cg;
    ocp[j] = oc;
    ohp[j] = og * tanhf(oc);
  }
  *(float4*)(ic + sb) = ocv;
  *(float4*)(out + 4718592 + sb) = ocv;  // ocT tail
  *(float4*)(cat2 + (size_t)b * 131072 + (size_t)(64 + c) * 1024 + px) = ohv;
}

// ---------------------------------------------------------------------------
// MFMA GEMM: C[b][m][n] = sum_k Wp[m][k] * (sum_{j<NX} X[j*1048576 + ...]) + b
// K, NX compile-time (rule #20: runtime K spilled frags to scratch in R8).
// NX>1 used only for z1 (zc partial slabs are contiguous, stride 1048576).
// ---------------------------------------------------------------------------
template <int K, int NX>
__global__ __launch_bounds__(256) void gemm_mfma_kernel(
    const unsigned short* __restrict__ Wp, const float* __restrict__ X,
    const float* __restrict__ bias, float* __restrict__ C, int xbs, int cbs)
{
  constexpr int KS = K + 8;
  constexpr int NKS = K / 32;
  int nt = blockIdx.x, mt = blockIdx.y, b = blockIdx.z;
  __shared__ __align__(16) unsigned short Xs[64 * KS];
  int tid = threadIdx.x, lane = tid & 63, w = tid >> 6;
  int n0 = nt * 64;
  const float* Xb = X + (size_t)b * xbs;

#pragma unroll
  for (int i = 0; i < K / 8; ++i) {
    int u = tid + i * 256;
    int c2 = u >> 6, nl = u & 63;
    size_t i0 = (size_t)(2 * c2) * 1024 + n0 + nl;
    size_t i1 = (size_t)(2 * c2 + 1) * 1024 + n0 + nl;
    float f0 = Xb[i0], f1 = Xb[i1];
#pragma unroll
    for (int j = 1; j < NX; ++j) {
      f0 += Xb[(size_t)j * 1048576 + i0];
      f1 += Xb[(size_t)j * 1048576 + i1];
    }
    ((unsigned*)Xs)[nl * (KS / 2) + c2] = pk2(f0, f1);
  }
  __syncthreads();

  int mrow = mt * 64 + w * 16 + (lane & 15);
  bf16x8 ka[NKS];
#pragma unroll
  for (int ks = 0; ks < NKS; ++ks)
    ka[ks] = *(const bf16x8*)&Wp[(size_t)mrow * K + ks * 32 + (lane >> 4) * 8];

  f32x4 acc[4] = {};
#pragma unroll
  for (int nf = 0; nf < 4; ++nf) {
#pragma unroll
    for (int ks = 0; ks < NKS; ++ks) {
      bf16x8 bx = *(const bf16x8*)&Xs[(nf * 16 + (lane & 15)) * KS +
                                      ks * 32 + (lane >> 4) * 8];
      acc[nf] = __builtin_amdgcn_mfma_f32_16x16x32_bf16(ka[ks], bx, acc[nf], 0, 0, 0);
    }
  }

  float* Cb = C + (size_t)b * cbs;
#pragma unroll
  for (int nf = 0; nf < 4; ++nf)
#pragma unroll
    for (int r = 0; r < 4; ++r) {
      int m = mt * 64 + w * 16 + (lane >> 4) * 4 + r;
      Cb[(size_t)m * 1024 + n0 + nf * 16 + (lane & 15)] = acc[nf][r] + bias[m];
    }
}

// ---------------------------------------------------------------------------
// Pack attention operands to bf16 once per step.
// slabs: 0 Qt (transpose), 1 Kht (transpose), 2 Kmt (transpose),
//        3 Vh (cast), 4 Vm (cast). Qt/Kt layout [b][1024 row][64 c].
// grid (16 nt, 5 slab, 8 b).
// ---------------------------------------------------------------------------
__global__ __launch_bounds__(256) void attpack_kernel(
    const float* __restrict__ qkv, const float* __restrict__ mkv,
    unsigned short* __restrict__ apack)
{
  int nt = blockIdx.x, slab = blockIdx.y, b = blockIdx.z;
  int tid = threadIdx.x;
  int n0 = nt * 64;
  const float* src;
  if (slab == 0)      src = qkv + (size_t)b * 196608;
  else if (slab == 1) src = qkv + (size_t)b * 196608 + 65536;
  else if (slab == 2) src = mkv + (size_t)b * 131072;
  else if (slab == 3) src = qkv + (size_t)b * 196608 + 131072;
  else                src = mkv + (size_t)b * 131072 + 65536;
  unsigned short* dst = apack + (size_t)slab * 524288 + (size_t)b * 65536;

  if (slab < 3) {
    __shared__ __align__(16) unsigned short T[64 * 72];
#pragma unroll
    for (int i = 0; i < 4; ++i) {
      int u = tid + i * 256;
      int c = u >> 4, n4 = (u & 15) * 4;
      float4 f = *(const float4*)(src + (size_t)c * 1024 + n0 + n4);
      T[(n4 + 0) * 72 + c] = f2bf(f.x);
      T[(n4 + 1) * 72 + c] = f2bf(f.y);
      T[(n4 + 2) * 72 + c] = f2bf(f.z);
      T[(n4 + 3) * 72 + c] = f2bf(f.w);
    }
    __syncthreads();
#pragma unroll
    for (int i = 0; i < 8; ++i) {
      int u = tid + i * 256;
      int nl = u >> 5, c2 = u & 31;
      ((unsigned*)dst)[(size_t)(n0 + nl) * 32 + c2] =
          ((const unsigned*)T)[nl * 36 + c2];
    }
  } else {
#pragma unroll
    for (int i = 0; i < 4; ++i) {
      int u = tid + i * 256;
      int c = u >> 4, n4 = (u & 15) * 4;
      float4 f = *(const float4*)(src + (size_t)c * 1024 + n0 + n4);
      unsigned* d = (unsigned*)&dst[(size_t)c * 1024 + n0 + n4];
      d[0] = pk2(f.x, f.y);
      d[1] = pk2(f.z, f.w);
    }
  }
}

// ---------------------------------------------------------------------------
// Attention pass 1 (MFMA, no LDS/barriers): per-n max & sumexp over m-half.
// Fragments loaded directly from packed global. grid (16 nt, 4, 8 b).
// ---------------------------------------------------------------------------
__global__ __launch_bounds__(256) void att_stats_kernel(
    const unsigned short* __restrict__ apack, float* __restrict__ stats)
{
  int nt = blockIdx.x;
  int att = blockIdx.y >> 1, mh = blockIdx.y & 1;
  int b = blockIdx.z;
  const unsigned short* Qtb = apack + (size_t)b * 65536;
  const unsigned short* Ktb = apack + (size_t)(att ? 2 : 1) * 524288 +
                              (size_t)b * 65536;
  int tid = threadIdx.x, lane = tid & 63, w = tid >> 6;
  int l15 = lane & 15, lh = lane >> 4;
  int nq = nt * 64 + w * 16 + l15;
  bf16x8 qa0 = *(const bf16x8*)&Qtb[(size_t)nq * 64 + lh * 8];
  bf16x8 qa1 = *(const bf16x8*)&Qtb[(size_t)nq * 64 + 32 + lh * 8];

  float M[4] = {-3.0e38f, -3.0e38f, -3.0e38f, -3.0e38f};
  float Dsum[4] = {0.f, 0.f, 0.f, 0.f};

  for (int mt = mh * 8; mt < mh * 8 + 8; ++mt) {
    f32x4 s[4];
#pragma unroll
    for (int mf = 0; mf < 4; ++mf) {
      int m = mt * 64 + mf * 16 + l15;
      bf16x8 b0 = *(const bf16x8*)&Ktb[(size_t)m * 64 + lh * 8];
      bf16x8 b1 = *(const bf16x8*)&Ktb[(size_t)m * 64 + 32 + lh * 8];
      f32x4 tacc = {};
      tacc = __builtin_amdgcn_mfma_f32_16x16x32_bf16(qa0, b0, tacc, 0, 0, 0);
      tacc = __builtin_amdgcn_mfma_f32_16x16x32_bf16(qa1, b1, tacc, 0, 0, 0);
      s[mf] = tacc;
    }
#pragma unroll
    for (int r = 0; r < 4; ++r) {
      float v0 = s[0][r], v1 = s[1][r], v2 = s[2][r], v3 = s[3][r];
      float mx = fmaxf(fmaxf(v0, v1), fmaxf(v2, v3));
      float nm = fmaxf(M[r], mx);
      Dsum[r] = Dsum[r] * __expf(M[r] - nm) +
                __expf(v0 - nm) + __expf(v1 - nm) +
                __expf(v2 - nm) + __expf(v3 - nm);
      M[r] = nm;
    }
  }
#pragma unroll
  for (int off = 1; off < 16; off <<= 1) {
#pragma unroll
    for (int r = 0; r < 4; ++r) {
      float Mo = __shfl_xor(M[r], off);
      float Do = __shfl_xor(Dsum[r], off);
      float nm = fmaxf(M[r], Mo);
      Dsum[r] = Dsum[r] * __expf(M[r] - nm) + Do * __expf(Mo - nm);
      M[r] = nm;
    }
  }
  if (l15 == 0) {
    float* stb = stats + (size_t)(((b * 2 + att) * 2 + mh) * 2) * 1024;
#pragma unroll
    for (int r = 0; r < 4; ++r) {
      int n = nt * 64 + w * 16 + lh * 4 + r;
      stb[n] = M[r];
      stb[1024 + n] = Dsum[r];
    }
  }
}

// ---------------------------------------------------------------------------
// Merge the two m-half stats -> stats2 [b][att][{M, 1/D}][1024]. grid 64.
// ---------------------------------------------------------------------------
__global__ __launch_bounds__(256) void statmerge_kernel(
    const float* __restrict__ stats, float* __restrict__ stats2)
{
  int i = blockIdx.x * 256 + threadIdx.x;  // < 16384
  int n = i & 1023, ba = i >> 10;
  const float* stb = stats + (size_t)ba * 4096;
  float M0 = stb[n], D0 = stb[1024 + n];
  float M1 = stb[2048 + n], D1 = stb[3072 + n];
  float Mm = fmaxf(M0, M1);
  float R = 1.0f / (D0 * __expf(M0 - Mm) + D1 * __expf(M1 - Mm));
  stats2[(size_t)ba * 2048 + n] = Mm;
  stats2[(size_t)ba * 2048 + 1024 + n] = R;
}

// ---------------------------------------------------------------------------
// Attention pass 2 (MFMA): Z[c][m] = sum_n V[c][n] * exp(S[n][m]-M[n])/D[n].
// 1/D folded into P at exp time. Fragments from packed global; LDS = Ps only.
// grid (16 mt, 8 = att*4+nq, 8 b) -> 4 partial-Z slabs (summed in z1 gemm).
// ---------------------------------------------------------------------------
__global__ __launch_bounds__(256) void att_z_kernel(
    const unsigned short* __restrict__ apack,
    const float* __restrict__ stats2, float* __restrict__ zc)
{
  int mt = blockIdx.x;
  int att = blockIdx.y >> 2, nh = blockIdx.y & 3;
  int b = blockIdx.z;
  const unsigned short* Qtb = apack + (size_t)b * 65536;
  const unsigned short* Ktb = apack + (size_t)(att ? 2 : 1) * 524288 +
                              (size_t)b * 65536;
  const unsigned short* Vtb = apack + (size_t)(att ? 4 : 3) * 524288 +
                              (size_t)b * 65536;
  const float* stM = stats2 + (size_t)(b * 2 + att) * 2048;
  const float* stR = stM + 1024;

  __shared__ __align__(16) unsigned short Ps[64 * 72];  // 9216 B

  int tid = threadIdx.x, lane = tid & 63, w = tid >> 6;
  int l15 = lane & 15, lh = lane >> 4;
  int m0 = mt * 64;

  bf16x8 bk[4][2];
#pragma unroll
  for (int mf = 0; mf < 4; ++mf) {
    int m = m0 + mf * 16 + l15;
    bk[mf][0] = *(const bf16x8*)&Ktb[(size_t)m * 64 + lh * 8];
    bk[mf][1] = *(const bf16x8*)&Ktb[(size_t)m * 64 + 32 + lh * 8];
  }

  f32x4 zacc[4] = {};

  for (int ntb = nh * 4; ntb < nh * 4 + 4; ++ntb) {
    int n0 = ntb * 64;
    int nq = n0 + w * 16 + l15;
    bf16x8 qa0 = *(const bf16x8*)&Qtb[(size_t)nq * 64 + lh * 8];
    bf16x8 qa1 = *(const bf16x8*)&Qtb[(size_t)nq * 64 + 32 + lh * 8];
    float mr[4], rr[4];
#pragma unroll
    for (int r = 0; r < 4; ++r) {
      int n = n0 + w * 16 + lh * 4 + r;
      mr[r] = stM[n];
      rr[r] = stR[n];
    }
#pragma unroll
    for (int mf = 0; mf < 4; ++mf) {
      f32x4 tacc = {};
      tacc = __builtin_amdgcn_mfma_f32_16x16x32_bf16(qa0, bk[mf][0], tacc, 0, 0, 0);
      tacc = __builtin_amdgcn_mfma_f32_16x16x32_bf16(qa1, bk[mf][1], tacc, 0, 0, 0);
      unsigned* dst = (unsigned*)&Ps[(mf * 16 + l15) * 72 + w * 16 + lh * 4];
      dst[0] = pk2(__expf(tacc[0] - mr[0]) * rr[0],
                   __expf(tacc[1] - mr[1]) * rr[1]);
      dst[1] = pk2(__expf(tacc[2] - mr[2]) * rr[2],
                   __expf(tacc[3] - mr[3]) * rr[3]);
    }
    __syncthreads();

    int cv = w * 16 + l15;
    bf16x8 va0 = *(const bf16x8*)&Vtb[(size_t)cv * 1024 + n0 + lh * 8];
    bf16x8 va1 = *(const bf16x8*)&Vtb[(size_t)cv * 1024 + n0 + 32 + lh * 8];
#pragma unroll
    for (int mf = 0; mf < 4; ++mf) {
      bf16x8 p0 = *(const bf16x8*)&Ps[(mf * 16 + l15) * 72 + lh * 8];
      bf16x8 p1 = *(const bf16x8*)&Ps[(mf * 16 + l15) * 72 + 32 + lh * 8];
      zacc[mf] = __builtin_amdgcn_mfma_f32_16x16x32_bf16(va0, p0, zacc[mf], 0, 0, 0);
      zacc[mf] = __builtin_amdgcn_mfma_f32_16x16x32_bf16(va1, p1, zacc[mf], 0, 0, 0);
    }
    __syncthreads();  // Ps reused next iteration
  }

  float* zb = zc + (size_t)nh * 1048576 + (size_t)b * 131072 +
              (size_t)att * 65536;
#pragma unroll
  for (int mf = 0; mf < 4; ++mf)
#pragma unroll
    for (int r = 0; r < 4; ++r) {
      int c = w * 16 + lh * 4 + r;
      zb[(size_t)c * 1024 + m0 + mf * 16 + l15] = zacc[mf][r];
    }
}

// ---------------------------------------------------------------------------
// SAM output gating.
// ---------------------------------------------------------------------------
__global__ __launch_bounds__(256) void sam_kernel(
    const float* __restrict__ g2, float* __restrict__ im,
    float* __restrict__ ih, float* __restrict__ out, int t)
{
  int c = blockIdx.x; int b = blockIdx.y;
  int px = threadIdx.x * 4;
  size_t gb = (size_t)b * 196608 + (size_t)c * 1024 + px;
  float4 vo4 = *(const float4*)(g2 + gb);
  float4 vg4 = *(const float4*)(g2 + gb + 65536);
  float4 vi4 = *(const float4*)(g2 + gb + 131072);
  size_t sb = (size_t)b * 65536 + (size_t)c * 1024 + px;
  float4 vm4 = *(const float4*)(im + sb);
  float* vop = (float*)&vo4; float* vgp = (float*)&vg4;
  float* vip = (float*)&vi4; float* vmp = (float*)&vm4;
  float4 om4, oh4;
  float* omp = (float*)&om4; float* ohp = (float*)&oh4;
#pragma unroll
  for (int j = 0; j < 4; ++j) {
    float ig = sigm(vip[j]);
    float om = tanhf(vgp[j]) * ig + (1.0f - ig) * vmp[j];
    omp[j] = om;
    ohp[j] = sigm(vop[j]) * om;
  }
  *(float4*)(im + sb) = om4;
  *(float4*)(ih + sb) = oh4;
  *(float4*)(out + ((size_t)(b * 8 + t) * 64 + c) * 1024 + px) = oh4;
  *(float4*)(out + 4194304 + sb) = oh4;  // ohT tail
  *(float4*)(out + 5242880 + sb) = om4;  // imT tail
}

// ---------------------------------------------------------------------------
extern "C" void kernel_launch(void* const* d_in, const int* in_sizes, int n_in,
                              void* d_out, int out_size, void* d_ws,
                              size_t ws_size, hipStream_t stream)
{
  const float* x      = (const float*)d_in[0];
  const float* conv_w = (const float*)d_in[1];
  const float* conv_b = (const float*)d_in[2];
  const float* gn_g   = (const float*)d_in[3];
  const float* gn_b   = (const float*)d_in[4];
  const float* h_w    = (const float*)d_in[5];
  const float* h_b    = (const float*)d_in[6];
  const float* m_w    = (const float*)d_in[7];
  const float* m_b    = (const float*)d_in[8];
  const float* z1_w   = (const float*)d_in[9];
  const float* z1_b   = (const float*)d_in[10];
  const float* z2_w   = (const float*)d_in[11];
  const float* z2_b   = (const float*)d_in[12];
  float* out = (float*)d_out;
  float* ws  = (float*)d_ws;

  float* ic     = ws;
  float* ih     = ws + 524288;
  float* im     = ws + 1048576;
  float* gates  = ws + 1572864;
  float* gnst   = ws + 3670016;
  float* qkv    = ws + 3670272;
  float* mkv    = ws + 5243136;
  float* stats  = ws + 6291712;
  float* cat2   = ws + 6357248;
  float* stats2 = ws + 7405824;
  unsigned short* wpack = (unsigned short*)(ws + 7438592);
  unsigned short* wproj = (unsigned short*)(ws + 7622912);
  unsigned short* apack = (unsigned short*)(ws + 7649536);
  float* zc     = ws + 8960256;
  float* g2     = gates;              // reuse after gnlstm

  const unsigned short* hp  = wproj;
  const unsigned short* mp  = wproj + 12288;
  const unsigned short* z1p = wproj + 20480;
  const unsigned short* z2p = wproj + 28672;

  // zero initial states ih, ic, im (contiguous)
  hipMemsetAsync(ic, 0, (size_t)3 * 524288 * sizeof(float), stream);
  // prepack weights
  wprep_kernel<<<dim3(1440), 256, 0, stream>>>(conv_w, wpack);
  wproj_kernel<<<dim3(208), 256, 0, stream>>>(h_w, m_w, z1_w, z2_w, wproj);

  for (int t = 0; t < 8; ++t) {
    conv3_mfma_kernel<<<dim3(16, 8, 2), 256, 0, stream>>>(
        x, ih, wpack, conv_b, gates, t);
    gnstats_kernel<<<dim3(8, 8), 256, 0, stream>>>(gates, gnst);
    gnlstm_kernel<<<dim3(64, 8), 256, 0, stream>>>(gates, gnst, gn_g,
                                                   gn_b, ic, cat2, out);
    // projections: h_qkv = h_w @ oh (cat2 rows 64-127); m_kv = m_w @ im
    gemm_mfma_kernel<64, 1><<<dim3(16, 3, 8), 256, 0, stream>>>(
        hp, cat2 + 65536, h_b, qkv, 131072, 196608);
    gemm_mfma_kernel<64, 1><<<dim3(16, 2, 8), 256, 0, stream>>>(
        mp, im, m_b, mkv, 65536, 131072);
    attpack_kernel<<<dim3(16, 5, 8), 256, 0, stream>>>(qkv, mkv, apack);
    att_stats_kernel<<<dim3(16, 4, 8), 256, 0, stream>>>(apack, stats);
    statmerge_kernel<<<dim3(64), 256, 0, stream>>>(stats, stats2);
    att_z_kernel<<<dim3(16, 8, 8), 256, 0, stream>>>(apack, stats2, zc);
    // z1: Zc = z1_w @ (zc0+zc1+zc2+zc3) -> cat2 top half
    gemm_mfma_kernel<128, 4><<<dim3(16, 1, 8), 256, 0, stream>>>(
        z1p, zc, z1_b, cat2, 131072, 131072);
    // z2: gates2 = z2_w @ cat2
    gemm_mfma_kernel<128, 1><<<dim3(16, 3, 8), 256, 0, stream>>>(
        z2p, cat2, z2_b, g2, 131072, 196608);
    sam_kernel<<<dim3(64, 8), 256, 0, stream>>>(g2, im, ih, out, t);
  }
}